// Round 1
// baseline (1141.051 us; speedup 1.0000x reference)
//
#include <hip/hip_runtime.h>

#define B_  2
#define T_  2048
#define D_  512
#define DM_ 64
#define H_  16
#define NQ_ (DM_*H_)   // 1024

// ---------------------------------------------------------------------------
// pad kernel: padbias[b*T+t] = (sum(mask[b,t,:]) == 0) ? -1e9 : 0
// ---------------------------------------------------------------------------
__global__ __launch_bounds__(64)
void pad_kernel(const float* __restrict__ mask, float* __restrict__ padb)
{
    const int row  = blockIdx.x;           // b*T + t
    const int lane = threadIdx.x;
    const float* p = mask + (size_t)row * D_;
    float4 a = *(const float4*)&p[lane * 8];
    float4 b = *(const float4*)&p[lane * 8 + 4];
    float s = a.x + a.y + a.z + a.w + b.x + b.y + b.z + b.w;
#pragma unroll
    for (int off = 32; off; off >>= 1) s += __shfl_down(s, off);
    if (lane == 0) padb[row] = (s == 0.0f) ? -1e9f : 0.0f;
}

// ---------------------------------------------------------------------------
// GEMM: out = (A[M,K] @ W[K,N] + bias[N]) * alpha
// HM=true : N==1024, write head-major Qh[((b*16+h)*T + t)*64 + dm], h=j%16, dm=j/16
// HM=false: write row-major out[m*N + j]
// 64x64 tile, K_T=32, 256 threads, 4x4 per thread.
// ---------------------------------------------------------------------------
template<bool HM>
__global__ __launch_bounds__(256)
void gemm_kernel(const float* __restrict__ A, const float* __restrict__ W,
                 const float* __restrict__ bias, float* __restrict__ out,
                 int M, int N, int K, float alpha)
{
    __shared__ float As[64][33];   // stride 33: a-reads conflict-free
    __shared__ float Bs[32][64];

    const int tid = threadIdx.x;
    const int tx = tid & 15, ty = tid >> 4;
    const int m0 = blockIdx.y * 64;
    const int j0 = blockIdx.x * 64;

    const int ar = tid >> 2;            // 0..63
    const int ac = (tid & 3) * 8;       // 0,8,16,24
    const int br = tid >> 4;            // 0..15
    const int bc = (tid & 15) * 4;      // 0..60

    float acc[4][4] = {};

    for (int k0 = 0; k0 < K; k0 += 32) {
        // A tile 64x32
        float4 a0 = *(const float4*)&A[(size_t)(m0 + ar) * K + k0 + ac];
        float4 a1 = *(const float4*)&A[(size_t)(m0 + ar) * K + k0 + ac + 4];
        As[ar][ac + 0] = a0.x; As[ar][ac + 1] = a0.y;
        As[ar][ac + 2] = a0.z; As[ar][ac + 3] = a0.w;
        As[ar][ac + 4] = a1.x; As[ar][ac + 5] = a1.y;
        As[ar][ac + 6] = a1.z; As[ar][ac + 7] = a1.w;
        // B tile 32x64
        float4 w0 = *(const float4*)&W[(size_t)(k0 + br) * N + j0 + bc];
        float4 w1 = *(const float4*)&W[(size_t)(k0 + br + 16) * N + j0 + bc];
        *(float4*)&Bs[br][bc]      = w0;
        *(float4*)&Bs[br + 16][bc] = w1;
        __syncthreads();

#pragma unroll
        for (int kk = 0; kk < 32; ++kk) {
            float a[4], b[4];
#pragma unroll
            for (int i = 0; i < 4; ++i) a[i] = As[ty * 4 + i][kk];
            if (HM) {
#pragma unroll
                for (int j = 0; j < 4; ++j) b[j] = Bs[kk][j * 16 + tx];
            } else {
                float4 b4 = *(const float4*)&Bs[kk][tx * 4];
                b[0] = b4.x; b[1] = b4.y; b[2] = b4.z; b[3] = b4.w;
            }
#pragma unroll
            for (int i = 0; i < 4; ++i)
#pragma unroll
                for (int j = 0; j < 4; ++j)
                    acc[i][j] = fmaf(a[i], b[j], acc[i][j]);
        }
        __syncthreads();
    }

    if (HM) {
        float bb0 = bias[j0 + 0 * 16 + tx];
        float bb1 = bias[j0 + 1 * 16 + tx];
        float bb2 = bias[j0 + 2 * 16 + tx];
        float bb3 = bias[j0 + 3 * 16 + tx];
        const int dm0 = j0 >> 4;
#pragma unroll
        for (int i = 0; i < 4; ++i) {
            int m = m0 + ty * 4 + i;
            int t = m & (T_ - 1), bidx = m >> 11;
            float4 v;
            v.x = (acc[i][0] + bb0) * alpha;
            v.y = (acc[i][1] + bb1) * alpha;
            v.z = (acc[i][2] + bb2) * alpha;
            v.w = (acc[i][3] + bb3) * alpha;
            *(float4*)&out[(((size_t)(bidx * H_ + tx)) * T_ + t) * DM_ + dm0] = v;
        }
    } else {
        float bb0 = bias[j0 + tx * 4 + 0];
        float bb1 = bias[j0 + tx * 4 + 1];
        float bb2 = bias[j0 + tx * 4 + 2];
        float bb3 = bias[j0 + tx * 4 + 3];
#pragma unroll
        for (int i = 0; i < 4; ++i) {
            int m = m0 + ty * 4 + i;
            float4 v;
            v.x = (acc[i][0] + bb0) * alpha;
            v.y = (acc[i][1] + bb1) * alpha;
            v.z = (acc[i][2] + bb2) * alpha;
            v.w = (acc[i][3] + bb3) * alpha;
            *(float4*)&out[(size_t)m * N + j0 + tx * 4] = v;
        }
    }
}

// ---------------------------------------------------------------------------
// Flash attention fp32: grid (T/64, B*H), block 256.
// Q pre-scaled by 1/8 at projection. ctx written merged [b,t,h*64+dm].
// ---------------------------------------------------------------------------
__global__ __launch_bounds__(256)
void attn_kernel(const float* __restrict__ Qh, const float* __restrict__ Kh,
                 const float* __restrict__ Vh, const float* __restrict__ padb,
                 float* __restrict__ ctx)
{
    __shared__ float Qs[64][65];
    __shared__ float KVs[64][65];   // K tile, then reused for V tile
    __shared__ float Ss[64][65];
    __shared__ float pb[64];
    __shared__ float mrow[64], lrow[64], rscale[64];

    const int tid = threadIdx.x;
    const int tx = tid & 15, ty = tid >> 4;
    const int q0 = blockIdx.x * 64;
    const int bh = blockIdx.y;             // b*16 + h
    const int bb = bh >> 4;
    const int hh = bh & 15;

    const float* Qbase = Qh + (size_t)bh * T_ * DM_;
    const float* Kbase = Kh + (size_t)bh * T_ * DM_;
    const float* Vbase = Vh + (size_t)bh * T_ * DM_;

    // Q tile 64x64 -> LDS
#pragma unroll
    for (int l = 0; l < 4; ++l) {
        int flat = l * 1024 + tid * 4;
        int r = flat >> 6, c = flat & 63;
        float4 q4 = *(const float4*)&Qbase[(size_t)(q0 + r) * DM_ + c];
        Qs[r][c] = q4.x; Qs[r][c + 1] = q4.y; Qs[r][c + 2] = q4.z; Qs[r][c + 3] = q4.w;
    }
    if (tid < 64) { mrow[tid] = -1e30f; lrow[tid] = 0.f; }

    float o[4][4] = {};

    for (int kt = 0; kt < T_; kt += 64) {
        __syncthreads();   // prev PV done before overwriting KVs
        // K tile
#pragma unroll
        for (int l = 0; l < 4; ++l) {
            int flat = l * 1024 + tid * 4;
            int r = flat >> 6, c = flat & 63;
            float4 k4 = *(const float4*)&Kbase[(size_t)(kt + r) * DM_ + c];
            KVs[r][c] = k4.x; KVs[r][c + 1] = k4.y; KVs[r][c + 2] = k4.z; KVs[r][c + 3] = k4.w;
        }
        if (tid < 64) pb[tid] = padb[bb * T_ + kt + tid];
        __syncthreads();

        // S = Q K^T (+ pad bias)
        float s[4][4] = {};
#pragma unroll 8
        for (int kk = 0; kk < 64; ++kk) {
            float a[4], b[4];
#pragma unroll
            for (int i = 0; i < 4; ++i) a[i] = Qs[ty * 4 + i][kk];
#pragma unroll
            for (int j = 0; j < 4; ++j) b[j] = KVs[tx * 4 + j][kk];
#pragma unroll
            for (int i = 0; i < 4; ++i)
#pragma unroll
                for (int j = 0; j < 4; ++j)
                    s[i][j] = fmaf(a[i], b[j], s[i][j]);
        }
#pragma unroll
        for (int i = 0; i < 4; ++i)
#pragma unroll
            for (int j = 0; j < 4; ++j)
                Ss[ty * 4 + i][tx * 4 + j] = s[i][j] + pb[tx * 4 + j];
        __syncthreads();

        // wave0: online softmax row pass  ||  threads 64..255: load V tile
        if (tid < 64) {
            const int r = tid;
            float rm = mrow[r];
#pragma unroll 8
            for (int k = 0; k < 64; ++k) rm = fmaxf(rm, Ss[r][k]);
            float sc = __expf(mrow[r] - rm);
            float sum = 0.f;
#pragma unroll 8
            for (int k = 0; k < 64; ++k) {
                float p = __expf(Ss[r][k] - rm);
                Ss[r][k] = p;
                sum += p;
            }
            lrow[r] = lrow[r] * sc + sum;
            mrow[r] = rm;
            rscale[r] = sc;
        } else {
            for (int idx = tid - 64; idx < 1024; idx += 192) {
                int r = idx >> 4, c = (idx & 15) * 4;
                float4 v4 = *(const float4*)&Vbase[(size_t)(kt + r) * DM_ + c];
                KVs[r][c] = v4.x; KVs[r][c + 1] = v4.y; KVs[r][c + 2] = v4.z; KVs[r][c + 3] = v4.w;
            }
        }
        __syncthreads();

        // O = O*rscale + P @ V
        float rs[4];
#pragma unroll
        for (int i = 0; i < 4; ++i) rs[i] = rscale[ty * 4 + i];
#pragma unroll
        for (int i = 0; i < 4; ++i)
#pragma unroll
            for (int j = 0; j < 4; ++j) o[i][j] *= rs[i];
#pragma unroll 8
        for (int kk = 0; kk < 64; ++kk) {
            float a[4], b[4];
#pragma unroll
            for (int i = 0; i < 4; ++i) a[i] = Ss[ty * 4 + i][kk];
#pragma unroll
            for (int j = 0; j < 4; ++j) b[j] = KVs[kk][tx * 4 + j];
#pragma unroll
            for (int i = 0; i < 4; ++i)
#pragma unroll
                for (int j = 0; j < 4; ++j)
                    o[i][j] = fmaf(a[i], b[j], o[i][j]);
        }
    }
    __syncthreads();

#pragma unroll
    for (int i = 0; i < 4; ++i) {
        int t = q0 + ty * 4 + i;
        float linv = 1.0f / lrow[ty * 4 + i];
        float4 v;
        v.x = o[i][0] * linv; v.y = o[i][1] * linv;
        v.z = o[i][2] * linv; v.w = o[i][3] * linv;
        *(float4*)&ctx[((size_t)(bb * T_ + t)) * NQ_ + hh * DM_ + tx * 4] = v;
    }
}

// ---------------------------------------------------------------------------
extern "C" void kernel_launch(void* const* d_in, const int* in_sizes, int n_in,
                              void* d_out, int out_size, void* d_ws, size_t ws_size,
                              hipStream_t stream) {
    const float* data = (const float*)d_in[0];
    const float* mask = (const float*)d_in[1];
    const float* wq   = (const float*)d_in[2];
    const float* bq   = (const float*)d_in[3];
    const float* wk   = (const float*)d_in[4];
    const float* bk   = (const float*)d_in[5];
    const float* wv   = (const float*)d_in[6];
    const float* bv   = (const float*)d_in[7];
    const float* wo   = (const float*)d_in[8];
    const float* bo   = (const float*)d_in[9];
    float* out = (float*)d_out;

    float* ws   = (float*)d_ws;
    float* Qh   = ws;                               // 4Mi floats (16MB)
    float* Kh   = ws + (size_t)4 * 1024 * 1024;
    float* Vh   = ws + (size_t)8 * 1024 * 1024;
    float* CTX  = ws + (size_t)12 * 1024 * 1024;    // [4096][1024]
    float* padb = ws + (size_t)16 * 1024 * 1024;    // 4096 floats

    const int M = B_ * T_;   // 4096

    pad_kernel<<<M, 64, 0, stream>>>(mask, padb);

    dim3 gproj(NQ_ / 64, M / 64);
    gemm_kernel<true><<<gproj, 256, 0, stream>>>(data, wq, bq, Qh, M, NQ_, D_, 0.125f);
    gemm_kernel<true><<<gproj, 256, 0, stream>>>(data, wk, bk, Kh, M, NQ_, D_, 1.0f);
    gemm_kernel<true><<<gproj, 256, 0, stream>>>(data, wv, bv, Vh, M, NQ_, D_, 1.0f);

    dim3 gattn(T_ / 64, B_ * H_);
    attn_kernel<<<gattn, 256, 0, stream>>>(Qh, Kh, Vh, padb, CTX);

    dim3 gout(D_ / 64, M / 64);
    gemm_kernel<false><<<gout, 256, 0, stream>>>(CTX, wo, bo, out, M, D_, NQ_, 1.0f);
}

// Round 2
// 435.270 us; speedup vs baseline: 2.6215x; 2.6215x over previous
//
#include <hip/hip_runtime.h>
#include <hip/hip_bf16.h>

#define B_  2
#define T_  2048
#define D_  512
#define DM_ 64
#define H_  16
#define NQ_ (DM_*H_)   // 1024

typedef __bf16 bf16x8 __attribute__((ext_vector_type(8)));
typedef float  f32x4  __attribute__((ext_vector_type(4)));

static __device__ __forceinline__ unsigned short f2bf(float x) {
    __hip_bfloat16 h = __float2bfloat16(x);
    return *(unsigned short*)&h;
}

// ---------------------------------------------------------------------------
// pad kernel: padbias[b*T+t] = (sum(mask[b,t,:]) == 0) ? -1e9 : 0
// ---------------------------------------------------------------------------
__global__ __launch_bounds__(64)
void pad_kernel(const float* __restrict__ mask, float* __restrict__ padb)
{
    const int row  = blockIdx.x;
    const int lane = threadIdx.x;
    const float* p = mask + (size_t)row * D_;
    float4 a = *(const float4*)&p[lane * 8];
    float4 b = *(const float4*)&p[lane * 8 + 4];
    float s = a.x + a.y + a.z + a.w + b.x + b.y + b.z + b.w;
#pragma unroll
    for (int off = 32; off; off >>= 1) s += __shfl_down(s, off);
    if (lane == 0) padb[row] = (s == 0.0f) ? -1e9f : 0.0f;
}

// ---------------------------------------------------------------------------
// GEMM: out = (A[M,K] @ W[K,N] + bias[N]) * alpha   (fp32 compute)
// MODE 0: fp32 row-major out[m*N + j]
// MODE 1: bf16 head-major out[((b*16+h)*T + t)*64 + dm]   (h=j%16, dm=j/16)
// MODE 2: bf16 head-major TRANSPOSED out[((b*16+h)*64 + dm)*T + t]  (for V)
// ---------------------------------------------------------------------------
template<int MODE>
__global__ __launch_bounds__(256)
void gemm_kernel(const float* __restrict__ A, const float* __restrict__ W,
                 const float* __restrict__ bias, void* __restrict__ outv,
                 int M, int N, int K, float alpha)
{
    __shared__ float As[64][33];
    __shared__ float Bs[32][64];

    const int tid = threadIdx.x;
    const int tx = tid & 15, ty = tid >> 4;
    const int m0 = blockIdx.y * 64;
    const int j0 = blockIdx.x * 64;

    const int ar = tid >> 2;
    const int ac = (tid & 3) * 8;
    const int br = tid >> 4;
    const int bc = (tid & 15) * 4;

    float acc[4][4] = {};

    for (int k0 = 0; k0 < K; k0 += 32) {
        float4 a0 = *(const float4*)&A[(size_t)(m0 + ar) * K + k0 + ac];
        float4 a1 = *(const float4*)&A[(size_t)(m0 + ar) * K + k0 + ac + 4];
        As[ar][ac + 0] = a0.x; As[ar][ac + 1] = a0.y;
        As[ar][ac + 2] = a0.z; As[ar][ac + 3] = a0.w;
        As[ar][ac + 4] = a1.x; As[ar][ac + 5] = a1.y;
        As[ar][ac + 6] = a1.z; As[ar][ac + 7] = a1.w;
        float4 w0 = *(const float4*)&W[(size_t)(k0 + br) * N + j0 + bc];
        float4 w1 = *(const float4*)&W[(size_t)(k0 + br + 16) * N + j0 + bc];
        *(float4*)&Bs[br][bc]      = w0;
        *(float4*)&Bs[br + 16][bc] = w1;
        __syncthreads();

#pragma unroll
        for (int kk = 0; kk < 32; ++kk) {
            float a[4], b[4];
#pragma unroll
            for (int i = 0; i < 4; ++i) a[i] = As[ty * 4 + i][kk];
            if (MODE != 0) {
#pragma unroll
                for (int j = 0; j < 4; ++j) b[j] = Bs[kk][j * 16 + tx];
            } else {
                float4 b4 = *(const float4*)&Bs[kk][tx * 4];
                b[0] = b4.x; b[1] = b4.y; b[2] = b4.z; b[3] = b4.w;
            }
#pragma unroll
            for (int i = 0; i < 4; ++i)
#pragma unroll
                for (int j = 0; j < 4; ++j)
                    acc[i][j] = fmaf(a[i], b[j], acc[i][j]);
        }
        __syncthreads();
    }

    if (MODE != 0) {
        float bb0 = bias[j0 + 0 * 16 + tx];
        float bb1 = bias[j0 + 1 * 16 + tx];
        float bb2 = bias[j0 + 2 * 16 + tx];
        float bb3 = bias[j0 + 3 * 16 + tx];
        const int dm0 = j0 >> 4;
        unsigned short* o16 = (unsigned short*)outv;
#pragma unroll
        for (int i = 0; i < 4; ++i) {
            int m = m0 + ty * 4 + i;
            int t = m & (T_ - 1), bidx = m >> 11;
            float v0 = (acc[i][0] + bb0) * alpha;
            float v1 = (acc[i][1] + bb1) * alpha;
            float v2 = (acc[i][2] + bb2) * alpha;
            float v3 = (acc[i][3] + bb3) * alpha;
            if (MODE == 1) {
                ushort4 u;
                u.x = f2bf(v0); u.y = f2bf(v1); u.z = f2bf(v2); u.w = f2bf(v3);
                *(ushort4*)&o16[(((size_t)(bidx * H_ + tx)) * T_ + t) * DM_ + dm0] = u;
            } else { // MODE 2: V^T [bh][dm][t]
                size_t base = ((size_t)(bidx * H_ + tx)) * DM_ + dm0;
                o16[(base + 0) * T_ + t] = f2bf(v0);
                o16[(base + 1) * T_ + t] = f2bf(v1);
                o16[(base + 2) * T_ + t] = f2bf(v2);
                o16[(base + 3) * T_ + t] = f2bf(v3);
            }
        }
    } else {
        float bb0 = bias[j0 + tx * 4 + 0];
        float bb1 = bias[j0 + tx * 4 + 1];
        float bb2 = bias[j0 + tx * 4 + 2];
        float bb3 = bias[j0 + tx * 4 + 3];
        float* out = (float*)outv;
#pragma unroll
        for (int i = 0; i < 4; ++i) {
            int m = m0 + ty * 4 + i;
            float4 v;
            v.x = (acc[i][0] + bb0) * alpha;
            v.y = (acc[i][1] + bb1) * alpha;
            v.z = (acc[i][2] + bb2) * alpha;
            v.w = (acc[i][3] + bb3) * alpha;
            *(float4*)&out[(size_t)m * N + j0 + tx * 4] = v;
        }
    }
}

// ---------------------------------------------------------------------------
// MFMA flash attention, bf16 inputs fp32 accum.
// grid (T/64, B*H), block 256 (4 waves, 16 q-rows each).
// Qh,Kh: [bh][t][64] bf16.  Vt: [bh][64][t] bf16.  ctx: [b*T][1024] fp32.
// LDS tiles XOR-swizzled: byte ^= (row&7)<<4  (G4 fix for stride-128B reads).
// ---------------------------------------------------------------------------
__global__ __launch_bounds__(256)
void attn_kernel(const unsigned short* __restrict__ Qh,
                 const unsigned short* __restrict__ Kh,
                 const unsigned short* __restrict__ Vt,
                 const float* __restrict__ padb,
                 float* __restrict__ ctx)
{
    __shared__ __align__(16) unsigned short Ks[64 * 64];      // [key][d] swizzled
    __shared__ __align__(16) unsigned short Vs[64 * 64];      // [d][key] swizzled
    __shared__ __align__(16) unsigned short Ps[4][16 * 64];   // per-wave [q][key] swizzled
    __shared__ float pbs[64];

    const int tid  = threadIdx.x;
    const int w    = tid >> 6;
    const int l    = tid & 63;
    const int lo16 = l & 15;
    const int g    = l >> 4;         // 16-lane group 0..3

    const int q0 = blockIdx.x * 64;
    const int bh = blockIdx.y;
    const int bb = bh >> 4;
    const int hh = bh & 15;

    // Q fragments in registers: lane holds Q[qrow][kstep*32 + g*8 .. +8)
    const unsigned short* Qp =
        Qh + ((size_t)bh * T_ + q0 + w * 16 + lo16) * DM_ + g * 8;
    bf16x8 qf0 = *(const bf16x8*)(Qp);
    bf16x8 qf1 = *(const bf16x8*)(Qp + 32);

    const unsigned short* Kg0 = Kh + (size_t)bh * T_ * DM_;
    const unsigned short* Vg0 = Vt + (size_t)bh * DM_ * T_;

    f32x4 oa[4] = {{0,0,0,0},{0,0,0,0},{0,0,0,0},{0,0,0,0}};
    float m_run[4] = {-1e30f, -1e30f, -1e30f, -1e30f};
    float l_run[4] = {0.f, 0.f, 0.f, 0.f};

    unsigned short* Pw = &Ps[w][0];

    for (int kt = 0; kt < T_; kt += 64) {
        __syncthreads();   // previous tile fully consumed
        // ---- stage K tile [64 key][64 d] and V^T tile [64 d][64 key]
#pragma unroll
        for (int p = 0; p < 2; ++p) {
            int idx = p * 256 + tid;
            int row = idx >> 3, col = (idx & 7) * 8;
            bf16x8 kr = *(const bf16x8*)(Kg0 + (size_t)(kt + row) * DM_ + col);
            int kdst = (row * 128 + col * 2) ^ ((row & 7) << 4);
            *(bf16x8*)(Ks + (kdst >> 1)) = kr;
            bf16x8 vr = *(const bf16x8*)(Vg0 + (size_t)row * T_ + kt + col);
            int vdst = (row * 128 + col * 2) ^ ((row & 7) << 4);
            *(bf16x8*)(Vs + (vdst >> 1)) = vr;
        }
        if (tid < 64) pbs[tid] = padb[bb * T_ + kt + tid];
        __syncthreads();

        // ---- S = Q K^T  (M=q16, N=key, K=d)
        f32x4 sa[4] = {{0,0,0,0},{0,0,0,0},{0,0,0,0},{0,0,0,0}};
#pragma unroll
        for (int ks = 0; ks < 2; ++ks) {
            bf16x8 qf = ks ? qf1 : qf0;
#pragma unroll
            for (int nt = 0; nt < 4; ++nt) {
                int row = nt * 16 + lo16;
                int off = (row * 128 + ks * 64 + g * 16) ^ ((row & 7) << 4);
                bf16x8 kf = *(const bf16x8*)(Ks + (off >> 1));
                sa[nt] = __builtin_amdgcn_mfma_f32_16x16x32_bf16(qf, kf, sa[nt], 0, 0, 0);
            }
        }

        // ---- online softmax (rows: q=(g*4+j); cols distributed over 16 lanes x 4 nt)
        float pbv[4];
#pragma unroll
        for (int nt = 0; nt < 4; ++nt) pbv[nt] = pbs[nt * 16 + lo16];
        float sv[4][4];
#pragma unroll
        for (int nt = 0; nt < 4; ++nt)
#pragma unroll
            for (int j = 0; j < 4; ++j) sv[nt][j] = sa[nt][j] + pbv[nt];

        float rm[4], sc[4];
#pragma unroll
        for (int j = 0; j < 4; ++j)
            rm[j] = fmaxf(fmaxf(sv[0][j], sv[1][j]), fmaxf(sv[2][j], sv[3][j]));
#pragma unroll
        for (int off = 8; off; off >>= 1)
#pragma unroll
            for (int j = 0; j < 4; ++j) rm[j] = fmaxf(rm[j], __shfl_xor(rm[j], off));
#pragma unroll
        for (int j = 0; j < 4; ++j) {
            float nm = fmaxf(m_run[j], rm[j]);
            sc[j] = __expf(m_run[j] - nm);
            m_run[j] = nm;
        }
        float rs[4] = {0.f, 0.f, 0.f, 0.f};
        float pv[4][4];
#pragma unroll
        for (int nt = 0; nt < 4; ++nt)
#pragma unroll
            for (int j = 0; j < 4; ++j) {
                float p = __expf(sv[nt][j] - m_run[j]);
                pv[nt][j] = p;
                rs[j] += p;
            }
#pragma unroll
        for (int off = 8; off; off >>= 1)
#pragma unroll
            for (int j = 0; j < 4; ++j) rs[j] += __shfl_xor(rs[j], off);
#pragma unroll
        for (int j = 0; j < 4; ++j) l_run[j] = l_run[j] * sc[j] + rs[j];
#pragma unroll
        for (int nd = 0; nd < 4; ++nd)
#pragma unroll
            for (int j = 0; j < 4; ++j) oa[nd][j] *= sc[j];

        // ---- P -> per-wave LDS (bf16, swizzled), wave-local only
#pragma unroll
        for (int nt = 0; nt < 4; ++nt)
#pragma unroll
            for (int j = 0; j < 4; ++j) {
                int q = g * 4 + j;
                int key = nt * 16 + lo16;
                int off = (q * 128 + key * 2) ^ ((q & 7) << 4);
                Pw[off >> 1] = f2bf(pv[nt][j]);
            }

        // ---- O += P @ V   (M=q16, N=d, K=key)
#pragma unroll
        for (int ks = 0; ks < 2; ++ks) {
            int poff = (lo16 * 128 + ks * 64 + g * 16) ^ ((lo16 & 7) << 4);
            bf16x8 pf = *(const bf16x8*)(Pw + (poff >> 1));
#pragma unroll
            for (int nd = 0; nd < 4; ++nd) {
                int row = nd * 16 + lo16;
                int off = (row * 128 + ks * 64 + g * 16) ^ ((row & 7) << 4);
                bf16x8 vf = *(const bf16x8*)(Vs + (off >> 1));
                oa[nd] = __builtin_amdgcn_mfma_f32_16x16x32_bf16(pf, vf, oa[nd], 0, 0, 0);
            }
        }
    }

    // ---- epilogue: ctx[b*T + q][hh*64 + d] = O / l
    float linv[4];
#pragma unroll
    for (int j = 0; j < 4; ++j) linv[j] = 1.0f / l_run[j];
#pragma unroll
    for (int nd = 0; nd < 4; ++nd)
#pragma unroll
        for (int j = 0; j < 4; ++j) {
            int qrow = q0 + w * 16 + g * 4 + j;
            int d = nd * 16 + lo16;
            ctx[((size_t)(bb * T_ + qrow)) * NQ_ + hh * DM_ + d] = oa[nd][j] * linv[j];
        }
}

// ---------------------------------------------------------------------------
extern "C" void kernel_launch(void* const* d_in, const int* in_sizes, int n_in,
                              void* d_out, int out_size, void* d_ws, size_t ws_size,
                              hipStream_t stream) {
    const float* data = (const float*)d_in[0];
    const float* mask = (const float*)d_in[1];
    const float* wq   = (const float*)d_in[2];
    const float* bq   = (const float*)d_in[3];
    const float* wk   = (const float*)d_in[4];
    const float* bk   = (const float*)d_in[5];
    const float* wv   = (const float*)d_in[6];
    const float* bv   = (const float*)d_in[7];
    const float* wo   = (const float*)d_in[8];
    const float* bo   = (const float*)d_in[9];
    float* out = (float*)d_out;

    char* ws = (char*)d_ws;
    unsigned short* Qh  = (unsigned short*)(ws);                       // 8MB
    unsigned short* Kh  = (unsigned short*)(ws + (size_t)8  * 1024 * 1024);
    unsigned short* Vt  = (unsigned short*)(ws + (size_t)16 * 1024 * 1024);
    float*          CTX = (float*)         (ws + (size_t)24 * 1024 * 1024); // 16MB
    float*          padb= (float*)         (ws + (size_t)40 * 1024 * 1024);

    const int M = B_ * T_;   // 4096

    pad_kernel<<<M, 64, 0, stream>>>(mask, padb);

    dim3 gproj(NQ_ / 64, M / 64);
    gemm_kernel<1><<<gproj, 256, 0, stream>>>(data, wq, bq, Qh, M, NQ_, D_, 0.125f);
    gemm_kernel<1><<<gproj, 256, 0, stream>>>(data, wk, bk, Kh, M, NQ_, D_, 1.0f);
    gemm_kernel<2><<<gproj, 256, 0, stream>>>(data, wv, bv, Vt, M, NQ_, D_, 1.0f);

    dim3 gattn(T_ / 64, B_ * H_);
    attn_kernel<<<gattn, 256, 0, stream>>>(Qh, Kh, Vt, padb, CTX);

    dim3 gout(D_ / 64, M / 64);
    gemm_kernel<0><<<gout, 256, 0, stream>>>(CTX, wo, bo, out, M, D_, NQ_, 1.0f);
}

// Round 3
// 231.068 us; speedup vs baseline: 4.9382x; 1.8837x over previous
//
#include <hip/hip_runtime.h>
#include <hip/hip_bf16.h>

#define B_  2
#define T_  2048
#define D_  512
#define DM_ 64
#define H_  16
#define NQ_ (DM_*H_)   // 1024

typedef __bf16 bf16x8 __attribute__((ext_vector_type(8)));
typedef float  f32x4  __attribute__((ext_vector_type(4)));

static __device__ __forceinline__ unsigned short f2bf(float x) {
    __hip_bfloat16 h = __float2bfloat16(x);
    return *(unsigned short*)&h;
}

// ---------------------------------------------------------------------------
// pad: padb[b*T+t] = (sum(mask[b,t,:])==0) ? -1e9 : 0
// ---------------------------------------------------------------------------
__global__ __launch_bounds__(64)
void pad_kernel(const float* __restrict__ mask, float* __restrict__ padb)
{
    const int row  = blockIdx.x;
    const int lane = threadIdx.x;
    const float* p = mask + (size_t)row * D_;
    float4 a = *(const float4*)&p[lane * 8];
    float4 b = *(const float4*)&p[lane * 8 + 4];
    float s = a.x + a.y + a.z + a.w + b.x + b.y + b.z + b.w;
#pragma unroll
    for (int off = 32; off; off >>= 1) s += __shfl_down(s, off);
    if (lane == 0) padb[row] = (s == 0.0f) ? -1e9f : 0.0f;
}

// ---------------------------------------------------------------------------
// fp32 -> bf16 elementwise (n multiple of 8)
// ---------------------------------------------------------------------------
__global__ __launch_bounds__(256)
void cvt_kernel(const float* __restrict__ in, unsigned short* __restrict__ out, int n)
{
    int i = (blockIdx.x * 256 + threadIdx.x) * 8;
    if (i >= n) return;
    float4 a = *(const float4*)&in[i];
    float4 b = *(const float4*)&in[i + 4];
    ushort4 u0; u0.x = f2bf(a.x); u0.y = f2bf(a.y); u0.z = f2bf(a.z); u0.w = f2bf(a.w);
    ushort4 u1; u1.x = f2bf(b.x); u1.y = f2bf(b.y); u1.z = f2bf(b.z); u1.w = f2bf(b.w);
    *(ushort4*)&out[i]     = u0;
    *(ushort4*)&out[i + 4] = u1;
}

// ---------------------------------------------------------------------------
// weight transpose+cvt: in fp32 [R][C] -> out bf16 [C][R].  block (32,8).
// ---------------------------------------------------------------------------
__global__ __launch_bounds__(256)
void wtrans_kernel(const float* __restrict__ in, unsigned short* __restrict__ out,
                   int R, int C)
{
    __shared__ float t[32][33];
    const int tx = threadIdx.x, ty = threadIdx.y;
    const int c0 = blockIdx.x * 32, r0 = blockIdx.y * 32;
#pragma unroll
    for (int i = 0; i < 4; ++i)
        t[ty * 4 + i][tx] = in[(size_t)(r0 + ty * 4 + i) * C + c0 + tx];
    __syncthreads();
#pragma unroll
    for (int i = 0; i < 4; ++i)
        out[(size_t)(c0 + ty * 4 + i) * R + r0 + tx] = f2bf(t[tx][ty * 4 + i]);
}

// ---------------------------------------------------------------------------
// MFMA GEMM: C = A[M,K] @ Bt[N,K]^T + bias, bf16 in / fp32 acc.
// 128x128 tile, BK=64, 4 waves (2x2 of 64x64), swizzled LDS (slot ^= row&7).
// MODE 0: fp32 out[m*N+n] = acc + bias
// MODE 1: bf16 head-major out[((b*16+h)*T+t)*64+dm] = (acc+bias)*alpha, h=n%16, dm=n/16
// MODE 2: bf16 V^T out[((b*16+h)*64+dm)*T+t] = acc+bias
// ---------------------------------------------------------------------------
template<int MODE>
__global__ __launch_bounds__(256)
void mgemm_kernel(const unsigned short* __restrict__ A,
                  const unsigned short* __restrict__ Bt,
                  const float* __restrict__ bias, void* __restrict__ outv,
                  int M, int N, int K, float alpha)
{
    __shared__ __align__(16) unsigned short Al[128 * 64];
    __shared__ __align__(16) unsigned short Bl[128 * 64];

    const int tid = threadIdx.x;
    const int w  = tid >> 6, l = tid & 63;
    const int lo = l & 15,  g = l >> 4;
    const int wr = w >> 1,  wc = w & 1;
    const int m0 = blockIdx.y * 128, n0 = blockIdx.x * 128;

    const int sr = tid >> 3;   // staging row base (0..31), +32 per pass
    const int sc = tid & 7;    // 16B slot

    f32x4 acc[4][4] = {};

    for (int k0 = 0; k0 < K; k0 += 64) {
        __syncthreads();
#pragma unroll
        for (int p = 0; p < 4; ++p) {
            int r = p * 32 + sr;
            int slot = sc ^ (r & 7);
            bf16x8 av = *(const bf16x8*)&A [(size_t)(m0 + r) * K + k0 + sc * 8];
            *(bf16x8*)&Al[r * 64 + slot * 8] = av;
            bf16x8 bv = *(const bf16x8*)&Bt[(size_t)(n0 + r) * K + k0 + sc * 8];
            *(bf16x8*)&Bl[r * 64 + slot * 8] = bv;
        }
        __syncthreads();
#pragma unroll
        for (int kk = 0; kk < 2; ++kk) {
            bf16x8 af[4], bfr[4];
#pragma unroll
            for (int i = 0; i < 4; ++i) {
                int row = wr * 64 + i * 16 + lo;
                af[i]  = *(const bf16x8*)&Al[row * 64 + (((kk << 2) + g) ^ (row & 7)) * 8];
                int col = wc * 64 + i * 16 + lo;
                bfr[i] = *(const bf16x8*)&Bl[col * 64 + (((kk << 2) + g) ^ (col & 7)) * 8];
            }
#pragma unroll
            for (int i = 0; i < 4; ++i)
#pragma unroll
                for (int j = 0; j < 4; ++j)
                    acc[i][j] = __builtin_amdgcn_mfma_f32_16x16x32_bf16(af[i], bfr[j], acc[i][j], 0, 0, 0);
        }
    }

    const int mb = m0 + wr * 64 + g * 4;
    if (MODE == 0) {
        float* out = (float*)outv;
#pragma unroll
        for (int j = 0; j < 4; ++j) {
            int n = n0 + wc * 64 + j * 16 + lo;
            float bb = bias[n];
#pragma unroll
            for (int i = 0; i < 4; ++i)
#pragma unroll
                for (int jj = 0; jj < 4; ++jj) {
                    int m = mb + i * 16 + jj;
                    out[(size_t)m * N + n] = acc[i][j][jj] + bb;
                }
        }
    } else {
        unsigned short* o16 = (unsigned short*)outv;
        float bb[4];
#pragma unroll
        for (int j = 0; j < 4; ++j) bb[j] = bias[n0 + wc * 64 + j * 16 + lo];
        const int head = lo;
        const int dmb  = (n0 >> 4) + wc * 4;
        if (MODE == 1) {
#pragma unroll
            for (int i = 0; i < 4; ++i)
#pragma unroll
                for (int jj = 0; jj < 4; ++jj) {
                    int m = mb + i * 16 + jj;
                    int t = m & (T_ - 1), bidx = m >> 11;
                    ushort4 u;
                    u.x = f2bf((acc[i][0][jj] + bb[0]) * alpha);
                    u.y = f2bf((acc[i][1][jj] + bb[1]) * alpha);
                    u.z = f2bf((acc[i][2][jj] + bb[2]) * alpha);
                    u.w = f2bf((acc[i][3][jj] + bb[3]) * alpha);
                    *(ushort4*)&o16[(((size_t)(bidx * H_ + head)) * T_ + t) * DM_ + dmb] = u;
                }
        } else {  // MODE 2: V^T [bh][dm][t]
#pragma unroll
            for (int i = 0; i < 4; ++i)
#pragma unroll
                for (int j = 0; j < 4; ++j) {
                    int m = mb + i * 16;             // jj spans t contiguously
                    int t = m & (T_ - 1), bidx = m >> 11;
                    ushort4 u;
                    u.x = f2bf(acc[i][j][0] + bb[j]);
                    u.y = f2bf(acc[i][j][1] + bb[j]);
                    u.z = f2bf(acc[i][j][2] + bb[j]);
                    u.w = f2bf(acc[i][j][3] + bb[j]);
                    *(ushort4*)&o16[((size_t)(bidx * H_ + head) * DM_ + dmb + j) * T_ + t] = u;
                }
        }
    }
}

// ---------------------------------------------------------------------------
// MFMA flash attention, bf16/fp32-acc, base-2 softmax (Q pre-scaled by log2e/8).
// grid (T/64, B*H), block 256.  Qh,Kh: [bh][t][64].  Vt: [bh][64][t].
// ctx: bf16 [b*T][1024].
// ---------------------------------------------------------------------------
__global__ __launch_bounds__(256)
void attn_kernel(const unsigned short* __restrict__ Qh,
                 const unsigned short* __restrict__ Kh,
                 const unsigned short* __restrict__ Vt,
                 const float* __restrict__ padb,
                 unsigned short* __restrict__ ctx)
{
    __shared__ __align__(16) unsigned short Ks[64 * 64];
    __shared__ __align__(16) unsigned short Vs[64 * 64];
    __shared__ __align__(16) unsigned short Ps[4][16 * 64];
    __shared__ float pbs[64];

    const int tid  = threadIdx.x;
    const int w    = tid >> 6;
    const int l    = tid & 63;
    const int lo16 = l & 15;
    const int g    = l >> 4;

    const int q0 = blockIdx.x * 64;
    const int bh = blockIdx.y;
    const int bb = bh >> 4;
    const int hh = bh & 15;

    const unsigned short* Qp =
        Qh + ((size_t)bh * T_ + q0 + w * 16 + lo16) * DM_ + g * 8;
    bf16x8 qf0 = *(const bf16x8*)(Qp);
    bf16x8 qf1 = *(const bf16x8*)(Qp + 32);

    const unsigned short* Kg0 = Kh + (size_t)bh * T_ * DM_;
    const unsigned short* Vg0 = Vt + (size_t)bh * DM_ * T_;

    f32x4 oa[4] = {{0,0,0,0},{0,0,0,0},{0,0,0,0},{0,0,0,0}};
    float m_run[4] = {-1e30f, -1e30f, -1e30f, -1e30f};
    float l_run[4] = {0.f, 0.f, 0.f, 0.f};

    unsigned short* Pw = &Ps[w][0];

    for (int kt = 0; kt < T_; kt += 64) {
        __syncthreads();
#pragma unroll
        for (int p = 0; p < 2; ++p) {
            int idx = p * 256 + tid;
            int row = idx >> 3, col = (idx & 7) * 8;
            bf16x8 kr = *(const bf16x8*)(Kg0 + (size_t)(kt + row) * DM_ + col);
            int kdst = (row * 128 + col * 2) ^ ((row & 7) << 4);
            *(bf16x8*)(Ks + (kdst >> 1)) = kr;
            bf16x8 vr = *(const bf16x8*)(Vg0 + (size_t)row * T_ + kt + col);
            int vdst = (row * 128 + col * 2) ^ ((row & 7) << 4);
            *(bf16x8*)(Vs + (vdst >> 1)) = vr;
        }
        if (tid < 64) pbs[tid] = padb[bb * T_ + kt + tid];
        __syncthreads();

        // S = Q K^T (base-2 units)
        f32x4 sa[4] = {{0,0,0,0},{0,0,0,0},{0,0,0,0},{0,0,0,0}};
#pragma unroll
        for (int ks = 0; ks < 2; ++ks) {
            bf16x8 qf = ks ? qf1 : qf0;
#pragma unroll
            for (int nt = 0; nt < 4; ++nt) {
                int row = nt * 16 + lo16;
                int off = (row * 128 + ks * 64 + g * 16) ^ ((row & 7) << 4);
                bf16x8 kf = *(const bf16x8*)(Ks + (off >> 1));
                sa[nt] = __builtin_amdgcn_mfma_f32_16x16x32_bf16(qf, kf, sa[nt], 0, 0, 0);
            }
        }

        float pbv[4];
#pragma unroll
        for (int nt = 0; nt < 4; ++nt) pbv[nt] = pbs[nt * 16 + lo16];
        float sv[4][4];
#pragma unroll
        for (int nt = 0; nt < 4; ++nt)
#pragma unroll
            for (int j = 0; j < 4; ++j) sv[nt][j] = sa[nt][j] + pbv[nt];

        float rm[4], sc[4];
#pragma unroll
        for (int j = 0; j < 4; ++j)
            rm[j] = fmaxf(fmaxf(sv[0][j], sv[1][j]), fmaxf(sv[2][j], sv[3][j]));
#pragma unroll
        for (int off = 8; off; off >>= 1)
#pragma unroll
            for (int j = 0; j < 4; ++j) rm[j] = fmaxf(rm[j], __shfl_xor(rm[j], off));
#pragma unroll
        for (int j = 0; j < 4; ++j) {
            float nm = fmaxf(m_run[j], rm[j]);
            sc[j] = exp2f(m_run[j] - nm);
            m_run[j] = nm;
        }
        float rs[4] = {0.f, 0.f, 0.f, 0.f};
        float pv[4][4];
#pragma unroll
        for (int nt = 0; nt < 4; ++nt)
#pragma unroll
            for (int j = 0; j < 4; ++j) {
                float p = exp2f(sv[nt][j] - m_run[j]);
                pv[nt][j] = p;
                rs[j] += p;
            }
#pragma unroll
        for (int off = 8; off; off >>= 1)
#pragma unroll
            for (int j = 0; j < 4; ++j) rs[j] += __shfl_xor(rs[j], off);
#pragma unroll
        for (int j = 0; j < 4; ++j) l_run[j] = l_run[j] * sc[j] + rs[j];
#pragma unroll
        for (int nd = 0; nd < 4; ++nd)
#pragma unroll
            for (int j = 0; j < 4; ++j) oa[nd][j] *= sc[j];

#pragma unroll
        for (int nt = 0; nt < 4; ++nt)
#pragma unroll
            for (int j = 0; j < 4; ++j) {
                int q = g * 4 + j;
                int key = nt * 16 + lo16;
                int off = (q * 128 + key * 2) ^ ((q & 7) << 4);
                Pw[off >> 1] = f2bf(pv[nt][j]);
            }

#pragma unroll
        for (int ks = 0; ks < 2; ++ks) {
            int poff = (lo16 * 128 + ks * 64 + g * 16) ^ ((lo16 & 7) << 4);
            bf16x8 pf = *(const bf16x8*)(Pw + (poff >> 1));
#pragma unroll
            for (int nd = 0; nd < 4; ++nd) {
                int row = nd * 16 + lo16;
                int off = (row * 128 + ks * 64 + g * 16) ^ ((row & 7) << 4);
                bf16x8 vf = *(const bf16x8*)(Vs + (off >> 1));
                oa[nd] = __builtin_amdgcn_mfma_f32_16x16x32_bf16(pf, vf, oa[nd], 0, 0, 0);
            }
        }
    }

    float linv[4];
#pragma unroll
    for (int j = 0; j < 4; ++j) linv[j] = 1.0f / l_run[j];
#pragma unroll
    for (int nd = 0; nd < 4; ++nd)
#pragma unroll
        for (int j = 0; j < 4; ++j) {
            int qrow = q0 + w * 16 + g * 4 + j;
            int d = nd * 16 + lo16;
            ctx[((size_t)(bb * T_ + qrow)) * NQ_ + hh * DM_ + d] = f2bf(oa[nd][j] * linv[j]);
        }
}

// ---------------------------------------------------------------------------
extern "C" void kernel_launch(void* const* d_in, const int* in_sizes, int n_in,
                              void* d_out, int out_size, void* d_ws, size_t ws_size,
                              hipStream_t stream) {
    const float* data = (const float*)d_in[0];
    const float* mask = (const float*)d_in[1];
    const float* wq   = (const float*)d_in[2];
    const float* bq   = (const float*)d_in[3];
    const float* wk   = (const float*)d_in[4];
    const float* bk   = (const float*)d_in[5];
    const float* wv   = (const float*)d_in[6];
    const float* bv   = (const float*)d_in[7];
    const float* wo   = (const float*)d_in[8];
    const float* bo   = (const float*)d_in[9];
    float* out = (float*)d_out;

    char* ws = (char*)d_ws;
    const size_t MB = 1024 * 1024;
    unsigned short* Qh   = (unsigned short*)(ws);             // 8MB
    unsigned short* Kh   = (unsigned short*)(ws +  8 * MB);   // 8MB
    unsigned short* Vt   = (unsigned short*)(ws + 16 * MB);   // 8MB
    unsigned short* CTX  = (unsigned short*)(ws + 24 * MB);   // 8MB (bf16)
    unsigned short* dataB= (unsigned short*)(ws + 32 * MB);   // 4MB
    unsigned short* wqt  = (unsigned short*)(ws + 36 * MB);   // 1MB each
    unsigned short* wkt  = (unsigned short*)(ws + 37 * MB);
    unsigned short* wvt  = (unsigned short*)(ws + 38 * MB);
    unsigned short* wot  = (unsigned short*)(ws + 39 * MB);
    float*          padb = (float*)         (ws + 40 * MB);   // 16KB

    const int M = B_ * T_;                 // 4096
    const float alpha_q = 0.125f * 1.44269504089f;

    pad_kernel<<<M, 64, 0, stream>>>(mask, padb);
    cvt_kernel<<<(M * D_ / 8 + 255) / 256, 256, 0, stream>>>(data, dataB, M * D_);
    {
        dim3 blk(32, 8);
        wtrans_kernel<<<dim3(NQ_ / 32, D_ / 32), blk, 0, stream>>>(wq, wqt, D_, NQ_);
        wtrans_kernel<<<dim3(NQ_ / 32, D_ / 32), blk, 0, stream>>>(wk, wkt, D_, NQ_);
        wtrans_kernel<<<dim3(NQ_ / 32, D_ / 32), blk, 0, stream>>>(wv, wvt, D_, NQ_);
        wtrans_kernel<<<dim3(D_ / 32, NQ_ / 32), blk, 0, stream>>>(wo, wot, NQ_, D_);
    }

    dim3 gproj(NQ_ / 128, M / 128);        // (8, 32)
    mgemm_kernel<1><<<gproj, 256, 0, stream>>>(dataB, wqt, bq, Qh, M, NQ_, D_, alpha_q);
    mgemm_kernel<1><<<gproj, 256, 0, stream>>>(dataB, wkt, bk, Kh, M, NQ_, D_, 1.0f);
    mgemm_kernel<2><<<gproj, 256, 0, stream>>>(dataB, wvt, bv, Vt, M, NQ_, D_, 1.0f);

    dim3 gattn(T_ / 64, B_ * H_);
    attn_kernel<<<gattn, 256, 0, stream>>>(Qh, Kh, Vt, padb, CTX);

    dim3 gout(D_ / 128, M / 128);          // (4, 32)
    mgemm_kernel<0><<<gout, 256, 0, stream>>>(CTX, wot, bo, out, M, D_, NQ_, 1.0f);
}

// Round 4
// 152.682 us; speedup vs baseline: 7.4734x; 1.5134x over previous
//
#include <hip/hip_runtime.h>
#include <hip/hip_bf16.h>

#define B_  2
#define T_  2048
#define D_  512
#define DM_ 64
#define H_  16
#define NQ_ (DM_*H_)   // 1024

typedef __bf16 bf16x8 __attribute__((ext_vector_type(8)));
typedef float  f32x4  __attribute__((ext_vector_type(4)));

static __device__ __forceinline__ unsigned short f2bf(float x) {
    __hip_bfloat16 h = __float2bfloat16(x);
    return *(unsigned short*)&h;
}
static __device__ __forceinline__ unsigned int pack2bf(float a, float b) {
    return (unsigned int)f2bf(a) | ((unsigned int)f2bf(b) << 16);
}
// native exp2: single v_exp_f32; s_nop covers the TRANS-use wait state.
static __device__ __forceinline__ float exp2_(float x) {
    float r;
    asm("v_exp_f32 %0, %1\ns_nop 0" : "=v"(r) : "v"(x));
    return r;
}

// ---------------------------------------------------------------------------
__global__ __launch_bounds__(64)
void pad_kernel(const float* __restrict__ mask, float* __restrict__ padb)
{
    const int row  = blockIdx.x;
    const int lane = threadIdx.x;
    const float* p = mask + (size_t)row * D_;
    float4 a = *(const float4*)&p[lane * 8];
    float4 b = *(const float4*)&p[lane * 8 + 4];
    float s = a.x + a.y + a.z + a.w + b.x + b.y + b.z + b.w;
#pragma unroll
    for (int off = 32; off; off >>= 1) s += __shfl_down(s, off);
    if (lane == 0) padb[row] = (s == 0.0f) ? -1e9f : 0.0f;
}

// ---------------------------------------------------------------------------
__global__ __launch_bounds__(256)
void cvt_kernel(const float* __restrict__ in, unsigned short* __restrict__ out, int n)
{
    int i = (blockIdx.x * 256 + threadIdx.x) * 8;
    if (i >= n) return;
    float4 a = *(const float4*)&in[i];
    float4 b = *(const float4*)&in[i + 4];
    ushort4 u0; u0.x = f2bf(a.x); u0.y = f2bf(a.y); u0.z = f2bf(a.z); u0.w = f2bf(a.w);
    ushort4 u1; u1.x = f2bf(b.x); u1.y = f2bf(b.y); u1.z = f2bf(b.z); u1.w = f2bf(b.w);
    *(ushort4*)&out[i]     = u0;
    *(ushort4*)&out[i + 4] = u1;
}

// ---------------------------------------------------------------------------
__global__ __launch_bounds__(256)
void wtrans_kernel(const float* __restrict__ in, unsigned short* __restrict__ out,
                   int R, int C)
{
    __shared__ float t[32][33];
    const int tx = threadIdx.x, ty = threadIdx.y;
    const int c0 = blockIdx.x * 32, r0 = blockIdx.y * 32;
#pragma unroll
    for (int i = 0; i < 4; ++i)
        t[ty * 4 + i][tx] = in[(size_t)(r0 + ty * 4 + i) * C + c0 + tx];
    __syncthreads();
#pragma unroll
    for (int i = 0; i < 4; ++i)
        out[(size_t)(c0 + ty * 4 + i) * R + r0 + tx] = f2bf(t[tx][ty * 4 + i]);
}

// ---------------------------------------------------------------------------
// MFMA GEMM, double-buffered LDS, one barrier per K-step (T14 async-stage).
// C = A[M,K] @ Bt[N,K]^T + bias.  N-tile fixed 128.  MR = 128 or 64 row-tile.
// MODE 0: fp32 out[m*N+n]
// MODE 1: bf16 head-major out[((b*16+h)*T+t)*64+dm] * alpha (h=n%16, dm=n/16)
// MODE 2: bf16 V^T out[((b*16+h)*64+dm)*T+t]
// ---------------------------------------------------------------------------
template<int MODE, int MR>
__global__ __launch_bounds__(256)
void mgemm_kernel(const unsigned short* __restrict__ A,
                  const unsigned short* __restrict__ Bt,
                  const float* __restrict__ bias, void* __restrict__ outv,
                  int M, int N, int K, float alpha)
{
    constexpr int AP = MR / 32;      // A staging passes
    constexpr int I  = MR / 32;      // per-wave mfma row-tiles
    __shared__ __align__(16) unsigned short Al[2][MR * 64];
    __shared__ __align__(16) unsigned short Bl[2][128 * 64];

    const int tid = threadIdx.x;
    const int w  = tid >> 6, l = tid & 63;
    const int lo = l & 15,  g = l >> 4;
    const int wri = w >> 1, wci = w & 1;
    const int m0 = blockIdx.y * MR, n0 = blockIdx.x * 128;

    const int sr = tid >> 3;         // 0..31
    const int sc = tid & 7;
    const int slot = sc ^ (sr & 7);

    f32x4 acc[I][4] = {};
    const int nk = K >> 6;

    bf16x8 ar[AP], br[4];
    // prologue: load k-step 0, write buf0
#pragma unroll
    for (int p = 0; p < AP; ++p)
        ar[p] = *(const bf16x8*)&A [(size_t)(m0 + p * 32 + sr) * K + sc * 8];
#pragma unroll
    for (int p = 0; p < 4; ++p)
        br[p] = *(const bf16x8*)&Bt[(size_t)(n0 + p * 32 + sr) * K + sc * 8];
#pragma unroll
    for (int p = 0; p < AP; ++p)
        *(bf16x8*)&Al[0][(p * 32 + sr) * 64 + slot * 8] = ar[p];
#pragma unroll
    for (int p = 0; p < 4; ++p)
        *(bf16x8*)&Bl[0][(p * 32 + sr) * 64 + slot * 8] = br[p];
    __syncthreads();

    for (int t = 0; t < nk; ++t) {
        const int cur = t & 1;
        const bool hn = (t + 1 < nk);
        if (hn) {
            const int k0 = (t + 1) << 6;
#pragma unroll
            for (int p = 0; p < AP; ++p)
                ar[p] = *(const bf16x8*)&A [(size_t)(m0 + p * 32 + sr) * K + k0 + sc * 8];
#pragma unroll
            for (int p = 0; p < 4; ++p)
                br[p] = *(const bf16x8*)&Bt[(size_t)(n0 + p * 32 + sr) * K + k0 + sc * 8];
        }
#pragma unroll
        for (int kk = 0; kk < 2; ++kk) {
            bf16x8 af[I], bfr[4];
#pragma unroll
            for (int i = 0; i < I; ++i) {
                int row = wri * (MR / 2) + i * 16 + lo;
                af[i] = *(const bf16x8*)&Al[cur][row * 64 + ((((kk << 2) + g) ^ (row & 7)) << 3)];
            }
#pragma unroll
            for (int j = 0; j < 4; ++j) {
                int col = wci * 64 + j * 16 + lo;
                bfr[j] = *(const bf16x8*)&Bl[cur][col * 64 + ((((kk << 2) + g) ^ (col & 7)) << 3)];
            }
#pragma unroll
            for (int i = 0; i < I; ++i)
#pragma unroll
                for (int j = 0; j < 4; ++j)
                    acc[i][j] = __builtin_amdgcn_mfma_f32_16x16x32_bf16(af[i], bfr[j], acc[i][j], 0, 0, 0);
        }
        if (hn) {
            const int nxt = cur ^ 1;
#pragma unroll
            for (int p = 0; p < AP; ++p)
                *(bf16x8*)&Al[nxt][(p * 32 + sr) * 64 + slot * 8] = ar[p];
#pragma unroll
            for (int p = 0; p < 4; ++p)
                *(bf16x8*)&Bl[nxt][(p * 32 + sr) * 64 + slot * 8] = br[p];
        }
        __syncthreads();
    }

    const int mb = m0 + wri * (MR / 2) + g * 4;
    if (MODE == 0) {
        float* out = (float*)outv;
#pragma unroll
        for (int j = 0; j < 4; ++j) {
            int n = n0 + wci * 64 + j * 16 + lo;
            float bb = bias[n];
#pragma unroll
            for (int i = 0; i < I; ++i)
#pragma unroll
                for (int jj = 0; jj < 4; ++jj) {
                    int m = mb + i * 16 + jj;
                    out[(size_t)m * N + n] = acc[i][j][jj] + bb;
                }
        }
    } else {
        unsigned short* o16 = (unsigned short*)outv;
        float bb[4];
#pragma unroll
        for (int j = 0; j < 4; ++j) bb[j] = bias[n0 + wci * 64 + j * 16 + lo];
        const int head = lo;
        const int dmb  = (n0 >> 4) + wci * 4;
        if (MODE == 1) {
#pragma unroll
            for (int i = 0; i < I; ++i)
#pragma unroll
                for (int jj = 0; jj < 4; ++jj) {
                    int m = mb + i * 16 + jj;
                    int t = m & (T_ - 1), bidx = m >> 11;
                    ushort4 u;
                    u.x = f2bf((acc[i][0][jj] + bb[0]) * alpha);
                    u.y = f2bf((acc[i][1][jj] + bb[1]) * alpha);
                    u.z = f2bf((acc[i][2][jj] + bb[2]) * alpha);
                    u.w = f2bf((acc[i][3][jj] + bb[3]) * alpha);
                    *(ushort4*)&o16[(((size_t)(bidx * H_ + head)) * T_ + t) * DM_ + dmb] = u;
                }
        } else {
#pragma unroll
            for (int i = 0; i < I; ++i)
#pragma unroll
                for (int j = 0; j < 4; ++j) {
                    int m = mb + i * 16;
                    int t = m & (T_ - 1), bidx = m >> 11;
                    ushort4 u;
                    u.x = f2bf(acc[i][j][0] + bb[j]);
                    u.y = f2bf(acc[i][j][1] + bb[j]);
                    u.z = f2bf(acc[i][j][2] + bb[j]);
                    u.w = f2bf(acc[i][j][3] + bb[j]);
                    *(ushort4*)&o16[((size_t)(bidx * H_ + head) * DM_ + dmb + j) * T_ + t] = u;
                }
    }
    }
}

// ---------------------------------------------------------------------------
// MFMA flash attention, swapped operands (S^T = K·Q^T, O^T = V^T·P^T).
// Per lane: q = lane&15; softmax stats are lane-scalars.
// Double-buffered K/V LDS, one barrier per tile.  Base-2 softmax.
// ---------------------------------------------------------------------------
__global__ __launch_bounds__(256, 4)
void attn_kernel(const unsigned short* __restrict__ Qh,
                 const unsigned short* __restrict__ Kh,
                 const unsigned short* __restrict__ Vt,
                 const float* __restrict__ padb,
                 unsigned short* __restrict__ ctx)
{
    __shared__ __align__(16) unsigned short Ks[2][64 * 64];
    __shared__ __align__(16) unsigned short Vs[2][64 * 64];
    __shared__ __align__(16) unsigned short Ps[4][16 * 64];

    const int tid  = threadIdx.x;
    const int w    = tid >> 6;
    const int l    = tid & 63;
    const int lo16 = l & 15;
    const int g    = l >> 4;

    const int q0 = blockIdx.x * 64;
    const int bh = blockIdx.y;
    const int bb = bh >> 4;
    const int hh = bh & 15;

    const unsigned short* Qp =
        Qh + ((size_t)bh * T_ + q0 + w * 16 + lo16) * DM_ + g * 8;
    bf16x8 qf0 = *(const bf16x8*)(Qp);
    bf16x8 qf1 = *(const bf16x8*)(Qp + 32);

    const unsigned short* Kg0 = Kh + (size_t)bh * T_ * DM_;
    const unsigned short* Vg0 = Vt + (size_t)bh * DM_ * T_;

    // staging geometry: thread covers rows {sro, sro+32}, 8-elem slot sc8
    const int sro = tid >> 3;
    const int sc8 = tid & 7;
    const int sdst = (sro * 128 + sc8 * 16) ^ ((sro & 7) << 4);   // byte offset

    // prologue: tile 0 -> buf 0
    {
        bf16x8 k0 = *(const bf16x8*)(Kg0 + (size_t)sro * DM_ + sc8 * 8);
        bf16x8 k1 = *(const bf16x8*)(Kg0 + (size_t)(sro + 32) * DM_ + sc8 * 8);
        bf16x8 v0 = *(const bf16x8*)(Vg0 + (size_t)sro * T_ + sc8 * 8);
        bf16x8 v1 = *(const bf16x8*)(Vg0 + (size_t)(sro + 32) * T_ + sc8 * 8);
        *(bf16x8*)((char*)Ks[0] + sdst)        = k0;
        *(bf16x8*)((char*)Ks[0] + sdst + 4096) = k1;
        *(bf16x8*)((char*)Vs[0] + sdst)        = v0;
        *(bf16x8*)((char*)Vs[0] + sdst + 4096) = v1;
    }
    __syncthreads();

    f32x4 oa[4] = {{0,0,0,0},{0,0,0,0},{0,0,0,0},{0,0,0,0}};
    float m_run = -1e30f, l_run = 0.f;
    char* Pb = (char*)&Ps[w][0];

    for (int it = 0; it < T_ / 64; ++it) {
        const int cur = it & 1;
        const char* Kc = (const char*)Ks[cur];
        const char* Vc = (const char*)Vs[cur];
        const bool hn = (it + 1 < T_ / 64);
        bf16x8 nk0, nk1, nv0, nv1;
        if (hn) {
            const unsigned short* Kt = Kg0 + (size_t)(it + 1) * 64 * DM_;
            const unsigned short* Vt2 = Vg0 + (it + 1) * 64;
            nk0 = *(const bf16x8*)(Kt + (size_t)sro * DM_ + sc8 * 8);
            nk1 = *(const bf16x8*)(Kt + (size_t)(sro + 32) * DM_ + sc8 * 8);
            nv0 = *(const bf16x8*)(Vt2 + (size_t)sro * T_ + sc8 * 8);
            nv1 = *(const bf16x8*)(Vt2 + (size_t)(sro + 32) * T_ + sc8 * 8);
        }

        // ---- S^T = K · Q^T : lane holds S[key=nt*16+g*4+j][q=lo16]
        f32x4 sa[4] = {{0,0,0,0},{0,0,0,0},{0,0,0,0},{0,0,0,0}};
#pragma unroll
        for (int ks = 0; ks < 2; ++ks) {
            bf16x8 qf = ks ? qf1 : qf0;
#pragma unroll
            for (int nt = 0; nt < 4; ++nt) {
                int row = nt * 16 + lo16;
                int off = (row * 128 + ks * 64 + g * 16) ^ ((row & 7) << 4);
                bf16x8 kf = *(const bf16x8*)(Kc + off);
                sa[nt] = __builtin_amdgcn_mfma_f32_16x16x32_bf16(kf, qf, sa[nt], 0, 0, 0);
            }
        }

        // ---- softmax over this lane's 16 keys + cross-g reduce
        const float* pbp = padb + bb * T_ + it * 64 + g * 4;
        float p[16];
#pragma unroll
        for (int nt = 0; nt < 4; ++nt) {
            f32x4 pb4 = *(const f32x4*)(pbp + nt * 16);
#pragma unroll
            for (int j = 0; j < 4; ++j) p[nt * 4 + j] = sa[nt][j] + pb4[j];
        }
        float rm = p[0];
#pragma unroll
        for (int k = 1; k < 16; ++k) rm = fmaxf(rm, p[k]);
        rm = fmaxf(rm, __shfl_xor(rm, 16));
        rm = fmaxf(rm, __shfl_xor(rm, 32));
        float nm = fmaxf(m_run, rm);
        float scale = exp2_(m_run - nm);
        m_run = nm;
        float sum = 0.f;
#pragma unroll
        for (int k = 0; k < 16; ++k) {
            float e = exp2_(p[k] - nm);
            p[k] = e;
            sum += e;
        }
        sum += __shfl_xor(sum, 16);
        sum += __shfl_xor(sum, 32);
        l_run = l_run * scale + sum;
#pragma unroll
        for (int nd = 0; nd < 4; ++nd) oa[nd] *= scale;

        // ---- P^T pack -> per-wave LDS [q][key] (swizzled), 4x ds_write_b64
#pragma unroll
        for (int nt = 0; nt < 4; ++nt) {
            uint2 u;
            u.x = pack2bf(p[nt * 4 + 0], p[nt * 4 + 1]);
            u.y = pack2bf(p[nt * 4 + 2], p[nt * 4 + 3]);
            int wb = (lo16 * 128 + nt * 32 + g * 8) ^ ((lo16 & 7) << 4);
            *(uint2*)(Pb + wb) = u;
        }

        // ---- O^T += V^T · P^T
#pragma unroll
        for (int ks = 0; ks < 2; ++ks) {
            int poff = (lo16 * 128 + ks * 64 + g * 16) ^ ((lo16 & 7) << 4);
            bf16x8 pf = *(const bf16x8*)(Pb + poff);
#pragma unroll
            for (int nd = 0; nd < 4; ++nd) {
                int row = nd * 16 + lo16;
                int off = (row * 128 + ks * 64 + g * 16) ^ ((row & 7) << 4);
                bf16x8 vf = *(const bf16x8*)(Vc + off);
                oa[nd] = __builtin_amdgcn_mfma_f32_16x16x32_bf16(vf, pf, oa[nd], 0, 0, 0);
            }
        }

        // ---- stage next tile into alternate buffer, single barrier
        if (hn) {
            char* Kd = (char*)Ks[cur ^ 1];
            char* Vd = (char*)Vs[cur ^ 1];
            *(bf16x8*)(Kd + sdst)        = nk0;
            *(bf16x8*)(Kd + sdst + 4096) = nk1;
            *(bf16x8*)(Vd + sdst)        = nv0;
            *(bf16x8*)(Vd + sdst + 4096) = nv1;
        }
        __syncthreads();
    }

    // ---- epilogue: lane q = lo16, d = nd*16 + g*4 + j  -> 4x ushort4
    float linv = 1.0f / l_run;
    const size_t crow = ((size_t)(bb * T_ + q0 + w * 16 + lo16)) * NQ_ + hh * DM_;
#pragma unroll
    for (int nd = 0; nd < 4; ++nd) {
        ushort4 u;
        u.x = f2bf(oa[nd][0] * linv);
        u.y = f2bf(oa[nd][1] * linv);
        u.z = f2bf(oa[nd][2] * linv);
        u.w = f2bf(oa[nd][3] * linv);
        *(ushort4*)&ctx[crow + nd * 16 + g * 4] = u;
    }
}

// ---------------------------------------------------------------------------
extern "C" void kernel_launch(void* const* d_in, const int* in_sizes, int n_in,
                              void* d_out, int out_size, void* d_ws, size_t ws_size,
                              hipStream_t stream) {
    const float* data = (const float*)d_in[0];
    const float* mask = (const float*)d_in[1];
    const float* wq   = (const float*)d_in[2];
    const float* bq   = (const float*)d_in[3];
    const float* wk   = (const float*)d_in[4];
    const float* bk   = (const float*)d_in[5];
    const float* wv   = (const float*)d_in[6];
    const float* bv   = (const float*)d_in[7];
    const float* wo   = (const float*)d_in[8];
    const float* bo   = (const float*)d_in[9];
    float* out = (float*)d_out;

    char* ws = (char*)d_ws;
    const size_t MB = 1024 * 1024;
    unsigned short* Qh   = (unsigned short*)(ws);             // 8MB
    unsigned short* Kh   = (unsigned short*)(ws +  8 * MB);   // 8MB
    unsigned short* Vt   = (unsigned short*)(ws + 16 * MB);   // 8MB
    unsigned short* CTX  = (unsigned short*)(ws + 24 * MB);   // 8MB (bf16)
    unsigned short* dataB= (unsigned short*)(ws + 32 * MB);   // 4MB
    unsigned short* wqt  = (unsigned short*)(ws + 36 * MB);   // 1MB each
    unsigned short* wkt  = (unsigned short*)(ws + 37 * MB);
    unsigned short* wvt  = (unsigned short*)(ws + 38 * MB);
    unsigned short* wot  = (unsigned short*)(ws + 39 * MB);
    float*          padb = (float*)         (ws + 40 * MB);   // 16KB

    const int M = B_ * T_;                 // 4096
    const float alpha_q = 0.125f * 1.44269504089f;

    pad_kernel<<<M, 64, 0, stream>>>(mask, padb);
    cvt_kernel<<<(M * D_ / 8 + 255) / 256, 256, 0, stream>>>(data, dataB, M * D_);
    {
        dim3 blk(32, 8);
        wtrans_kernel<<<dim3(NQ_ / 32, D_ / 32), blk, 0, stream>>>(wq, wqt, D_, NQ_);
        wtrans_kernel<<<dim3(NQ_ / 32, D_ / 32), blk, 0, stream>>>(wk, wkt, D_, NQ_);
        wtrans_kernel<<<dim3(NQ_ / 32, D_ / 32), blk, 0, stream>>>(wv, wvt, D_, NQ_);
        wtrans_kernel<<<dim3(D_ / 32, NQ_ / 32), blk, 0, stream>>>(wo, wot, NQ_, D_);
    }

    dim3 gproj(NQ_ / 128, M / 128);        // (8, 32) -> 256 blocks
    mgemm_kernel<1, 128><<<gproj, 256, 0, stream>>>(dataB, wqt, bq, Qh, M, NQ_, D_, alpha_q);
    mgemm_kernel<1, 128><<<gproj, 256, 0, stream>>>(dataB, wkt, bk, Kh, M, NQ_, D_, 1.0f);
    mgemm_kernel<2, 128><<<gproj, 256, 0, stream>>>(dataB, wvt, bv, Vt, M, NQ_, D_, 1.0f);

    dim3 gattn(T_ / 64, B_ * H_);
    attn_kernel<<<gattn, 256, 0, stream>>>(Qh, Kh, Vt, padb, CTX);

    dim3 gout(D_ / 128, M / 64);           // (4, 64) -> 256 blocks
    mgemm_kernel<0, 64><<<gout, 256, 0, stream>>>(CTX, wot, bo, out, M, D_, NQ_, 1.0f);
}

// Round 5
// 115.087 us; speedup vs baseline: 9.9147x; 1.3267x over previous
//
#include <hip/hip_runtime.h>
#include <hip/hip_bf16.h>

#define B_  2
#define T_  2048
#define D_  512
#define DM_ 64
#define H_  16
#define NQ_ (DM_*H_)   // 1024

typedef __bf16 bf16x8 __attribute__((ext_vector_type(8)));
typedef float  f32x4  __attribute__((ext_vector_type(4)));

static __device__ __forceinline__ unsigned short f2bf(float x) {
    __hip_bfloat16 h = __float2bfloat16(x);
    return *(unsigned short*)&h;
}
static __device__ __forceinline__ unsigned int pack2bf(float a, float b) {
    return (unsigned int)f2bf(a) | ((unsigned int)f2bf(b) << 16);
}
static __device__ __forceinline__ float exp2_(float x) {
    float r;
    asm("v_exp_f32 %0, %1\ns_nop 0" : "=v"(r) : "v"(x));
    return r;
}

// ---------------------------------------------------------------------------
// fused prep: blocks [0,1024): pad rows (4/block); [1024,2048): fp32->bf16 cvt
// ---------------------------------------------------------------------------
__global__ __launch_bounds__(256)
void prep_kernel(const float* __restrict__ mask, float* __restrict__ padb,
                 const float* __restrict__ data, unsigned short* __restrict__ dataB)
{
    const int bid = blockIdx.x;
    if (bid < 1024) {
        const int row  = bid * 4 + (threadIdx.x >> 6);
        const int lane = threadIdx.x & 63;
        const float* p = mask + (size_t)row * D_;
        float4 a = *(const float4*)&p[lane * 8];
        float4 b = *(const float4*)&p[lane * 8 + 4];
        float s = a.x + a.y + a.z + a.w + b.x + b.y + b.z + b.w;
#pragma unroll
        for (int off = 32; off; off >>= 1) s += __shfl_down(s, off);
        if (lane == 0) padb[row] = (s == 0.0f) ? -1e9f : 0.0f;
    } else {
        int i = ((bid - 1024) * 256 + threadIdx.x) * 8;
        float4 a = *(const float4*)&data[i];
        float4 b = *(const float4*)&data[i + 4];
        ushort4 u0; u0.x = f2bf(a.x); u0.y = f2bf(a.y); u0.z = f2bf(a.z); u0.w = f2bf(a.w);
        ushort4 u1; u1.x = f2bf(b.x); u1.y = f2bf(b.y); u1.z = f2bf(b.z); u1.w = f2bf(b.w);
        *(ushort4*)&dataB[i]     = u0;
        *(ushort4*)&dataB[i + 4] = u1;
    }
}

// ---------------------------------------------------------------------------
// batched weight transpose+cvt for wq/wk/wv: [512][1024] -> Bt_all[z][1024][512]
// ---------------------------------------------------------------------------
__global__ __launch_bounds__(256)
void wtrans_qkv_kernel(const float* __restrict__ wq, const float* __restrict__ wk,
                       const float* __restrict__ wv, unsigned short* __restrict__ btall)
{
    __shared__ float t[32][33];
    const int tx = threadIdx.x, ty = threadIdx.y;
    const int c0 = blockIdx.x * 32, r0 = blockIdx.y * 32;
    const int z = blockIdx.z;
    const float* in = (z == 0) ? wq : (z == 1) ? wk : wv;
    unsigned short* out = btall + (size_t)z * NQ_ * D_;
#pragma unroll
    for (int i = 0; i < 4; ++i)
        t[ty * 4 + i][tx] = in[(size_t)(r0 + ty * 4 + i) * NQ_ + c0 + tx];
    __syncthreads();
#pragma unroll
    for (int i = 0; i < 4; ++i)
        out[(size_t)(c0 + ty * 4 + i) * D_ + r0 + tx] = f2bf(t[tx][ty * 4 + i]);
}

__global__ __launch_bounds__(256)
void wtrans_kernel(const float* __restrict__ in, unsigned short* __restrict__ out,
                   int R, int C)
{
    __shared__ float t[32][33];
    const int tx = threadIdx.x, ty = threadIdx.y;
    const int c0 = blockIdx.x * 32, r0 = blockIdx.y * 32;
#pragma unroll
    for (int i = 0; i < 4; ++i)
        t[ty * 4 + i][tx] = in[(size_t)(r0 + ty * 4 + i) * C + c0 + tx];
    __syncthreads();
#pragma unroll
    for (int i = 0; i < 4; ++i)
        out[(size_t)(c0 + ty * 4 + i) * R + r0 + tx] = f2bf(t[tx][ty * 4 + i]);
}

// ---------------------------------------------------------------------------
// fused QKV projection GEMM: A[4096,512] @ BtAll[3072,512]^T, dbuf LDS.
// Segment by n0: [0,1024)->Qh (head-major, *alpha_q), [1024,2048)->Kh,
// [2048,3072)->Vt (transposed [bh][dm][t]).
// ---------------------------------------------------------------------------
__global__ __launch_bounds__(256)
void mgemm_qkv_kernel(const unsigned short* __restrict__ A,
                      const unsigned short* __restrict__ BtAll,
                      const float* __restrict__ bq, const float* __restrict__ bk,
                      const float* __restrict__ bv,
                      unsigned short* __restrict__ Qh, unsigned short* __restrict__ Kh,
                      unsigned short* __restrict__ Vt, float alpha_q)
{
    const int K = D_;
    __shared__ __align__(16) unsigned short Al[2][128 * 64];
    __shared__ __align__(16) unsigned short Bl[2][128 * 64];

    const int tid = threadIdx.x;
    const int w  = tid >> 6, l = tid & 63;
    const int lo = l & 15,  g = l >> 4;
    const int wri = w >> 1, wci = w & 1;
    const int m0 = blockIdx.y * 128, n0 = blockIdx.x * 128;

    const int sr = tid >> 3;
    const int sc = tid & 7;
    const int slot = sc ^ (sr & 7);

    f32x4 acc[4][4] = {};
    const int nk = K >> 6;   // 8

    bf16x8 ar[4], br[4];
#pragma unroll
    for (int p = 0; p < 4; ++p) {
        ar[p] = *(const bf16x8*)&A    [(size_t)(m0 + p * 32 + sr) * K + sc * 8];
        br[p] = *(const bf16x8*)&BtAll[(size_t)(n0 + p * 32 + sr) * K + sc * 8];
    }
#pragma unroll
    for (int p = 0; p < 4; ++p) {
        *(bf16x8*)&Al[0][(p * 32 + sr) * 64 + slot * 8] = ar[p];
        *(bf16x8*)&Bl[0][(p * 32 + sr) * 64 + slot * 8] = br[p];
    }
    __syncthreads();

    for (int t = 0; t < nk; ++t) {
        const int cur = t & 1;
        const bool hn = (t + 1 < nk);
        if (hn) {
            const int k0 = (t + 1) << 6;
#pragma unroll
            for (int p = 0; p < 4; ++p) {
                ar[p] = *(const bf16x8*)&A    [(size_t)(m0 + p * 32 + sr) * K + k0 + sc * 8];
                br[p] = *(const bf16x8*)&BtAll[(size_t)(n0 + p * 32 + sr) * K + k0 + sc * 8];
            }
        }
#pragma unroll
        for (int kk = 0; kk < 2; ++kk) {
            bf16x8 af[4], bfr[4];
#pragma unroll
            for (int i = 0; i < 4; ++i) {
                int row = wri * 64 + i * 16 + lo;
                af[i] = *(const bf16x8*)&Al[cur][row * 64 + ((((kk << 2) + g) ^ (row & 7)) << 3)];
                int col = wci * 64 + i * 16 + lo;
                bfr[i] = *(const bf16x8*)&Bl[cur][col * 64 + ((((kk << 2) + g) ^ (col & 7)) << 3)];
            }
#pragma unroll
            for (int i = 0; i < 4; ++i)
#pragma unroll
                for (int j = 0; j < 4; ++j)
                    acc[i][j] = __builtin_amdgcn_mfma_f32_16x16x32_bf16(af[i], bfr[j], acc[i][j], 0, 0, 0);
        }
        if (hn) {
            const int nxt = cur ^ 1;
#pragma unroll
            for (int p = 0; p < 4; ++p) {
                *(bf16x8*)&Al[nxt][(p * 32 + sr) * 64 + slot * 8] = ar[p];
                *(bf16x8*)&Bl[nxt][(p * 32 + sr) * 64 + slot * 8] = br[p];
            }
        }
        __syncthreads();
    }

    const int seg = n0 >> 10;                  // 0:Q 1:K 2:V
    const int n0l = n0 & 1023;
    const float* bias = (seg == 0) ? bq : (seg == 1) ? bk : bv;
    const float alpha = (seg == 0) ? alpha_q : 1.0f;
    unsigned short* o16 = (seg == 0) ? Qh : (seg == 1) ? Kh : Vt;

    const int mb = m0 + wri * 64 + g * 4;
    float bb[4];
#pragma unroll
    for (int j = 0; j < 4; ++j) bb[j] = bias[n0l + wci * 64 + j * 16 + lo];
    const int head = lo;
    const int dmb  = (n0l >> 4) + wci * 4;
    if (seg < 2) {
#pragma unroll
        for (int i = 0; i < 4; ++i)
#pragma unroll
            for (int jj = 0; jj < 4; ++jj) {
                int m = mb + i * 16 + jj;
                int t = m & (T_ - 1), bidx = m >> 11;
                ushort4 u;
                u.x = f2bf((acc[i][0][jj] + bb[0]) * alpha);
                u.y = f2bf((acc[i][1][jj] + bb[1]) * alpha);
                u.z = f2bf((acc[i][2][jj] + bb[2]) * alpha);
                u.w = f2bf((acc[i][3][jj] + bb[3]) * alpha);
                *(ushort4*)&o16[(((size_t)(bidx * H_ + head)) * T_ + t) * DM_ + dmb] = u;
            }
    } else {
#pragma unroll
        for (int i = 0; i < 4; ++i)
#pragma unroll
            for (int j = 0; j < 4; ++j) {
                int m = mb + i * 16;
                int t = m & (T_ - 1), bidx = m >> 11;
                ushort4 u;
                u.x = f2bf(acc[i][j][0] + bb[j]);
                u.y = f2bf(acc[i][j][1] + bb[j]);
                u.z = f2bf(acc[i][j][2] + bb[j]);
                u.w = f2bf(acc[i][j][3] + bb[j]);
                *(ushort4*)&o16[((size_t)(bidx * H_ + head) * DM_ + dmb + j) * T_ + t] = u;
            }
    }
}

// ---------------------------------------------------------------------------
// out-projection GEMM (fp32 out), 64x128 tile, dbuf LDS.
// ---------------------------------------------------------------------------
__global__ __launch_bounds__(256)
void mgemm_out_kernel(const unsigned short* __restrict__ A,
                      const unsigned short* __restrict__ Bt,
                      const float* __restrict__ bias, float* __restrict__ out,
                      int M, int N, int K)
{
    __shared__ __align__(16) unsigned short Al[2][64 * 64];
    __shared__ __align__(16) unsigned short Bl[2][128 * 64];

    const int tid = threadIdx.x;
    const int w  = tid >> 6, l = tid & 63;
    const int lo = l & 15,  g = l >> 4;
    const int wri = w >> 1, wci = w & 1;
    const int m0 = blockIdx.y * 64, n0 = blockIdx.x * 128;

    const int sr = tid >> 3;
    const int sc = tid & 7;
    const int slot = sc ^ (sr & 7);

    f32x4 acc[2][4] = {};
    const int nk = K >> 6;

    bf16x8 ar[2], br[4];
#pragma unroll
    for (int p = 0; p < 2; ++p)
        ar[p] = *(const bf16x8*)&A [(size_t)(m0 + p * 32 + sr) * K + sc * 8];
#pragma unroll
    for (int p = 0; p < 4; ++p)
        br[p] = *(const bf16x8*)&Bt[(size_t)(n0 + p * 32 + sr) * K + sc * 8];
#pragma unroll
    for (int p = 0; p < 2; ++p)
        *(bf16x8*)&Al[0][(p * 32 + sr) * 64 + slot * 8] = ar[p];
#pragma unroll
    for (int p = 0; p < 4; ++p)
        *(bf16x8*)&Bl[0][(p * 32 + sr) * 64 + slot * 8] = br[p];
    __syncthreads();

    for (int t = 0; t < nk; ++t) {
        const int cur = t & 1;
        const bool hn = (t + 1 < nk);
        if (hn) {
            const int k0 = (t + 1) << 6;
#pragma unroll
            for (int p = 0; p < 2; ++p)
                ar[p] = *(const bf16x8*)&A [(size_t)(m0 + p * 32 + sr) * K + k0 + sc * 8];
#pragma unroll
            for (int p = 0; p < 4; ++p)
                br[p] = *(const bf16x8*)&Bt[(size_t)(n0 + p * 32 + sr) * K + k0 + sc * 8];
        }
#pragma unroll
        for (int kk = 0; kk < 2; ++kk) {
            bf16x8 af[2], bfr[4];
#pragma unroll
            for (int i = 0; i < 2; ++i) {
                int row = wri * 32 + i * 16 + lo;
                af[i] = *(const bf16x8*)&Al[cur][row * 64 + ((((kk << 2) + g) ^ (row & 7)) << 3)];
            }
#pragma unroll
            for (int j = 0; j < 4; ++j) {
                int col = wci * 64 + j * 16 + lo;
                bfr[j] = *(const bf16x8*)&Bl[cur][col * 64 + ((((kk << 2) + g) ^ (col & 7)) << 3)];
            }
#pragma unroll
            for (int i = 0; i < 2; ++i)
#pragma unroll
                for (int j = 0; j < 4; ++j)
                    acc[i][j] = __builtin_amdgcn_mfma_f32_16x16x32_bf16(af[i], bfr[j], acc[i][j], 0, 0, 0);
        }
        if (hn) {
            const int nxt = cur ^ 1;
#pragma unroll
            for (int p = 0; p < 2; ++p)
                *(bf16x8*)&Al[nxt][(p * 32 + sr) * 64 + slot * 8] = ar[p];
#pragma unroll
            for (int p = 0; p < 4; ++p)
                *(bf16x8*)&Bl[nxt][(p * 32 + sr) * 64 + slot * 8] = br[p];
        }
        __syncthreads();
    }

    const int mb = m0 + wri * 32 + g * 4;
#pragma unroll
    for (int j = 0; j < 4; ++j) {
        int n = n0 + wci * 64 + j * 16 + lo;
        float bb = bias[n];
#pragma unroll
        for (int i = 0; i < 2; ++i)
#pragma unroll
            for (int jj = 0; jj < 4; ++jj) {
                int m = mb + i * 16 + jj;
                out[(size_t)m * N + n] = acc[i][j][jj] + bb;
            }
    }
}

// ---------------------------------------------------------------------------
// MFMA flash attention, no-max softmax (scores bounded; pad -1e9 -> exp2 -> 0).
// QBLK=128 (32 q/wave), KVBLK=64, dbuf K/V LDS, one barrier/tile.
// S^T = K·Q^T, O^T = V^T·P^T; lane q = lo16 (+qt*16), softmax lane-local.
// ---------------------------------------------------------------------------
__global__ __launch_bounds__(256, 3)
void attn_kernel(const unsigned short* __restrict__ Qh,
                 const unsigned short* __restrict__ Kh,
                 const unsigned short* __restrict__ Vt,
                 const float* __restrict__ padb,
                 unsigned short* __restrict__ ctx)
{
    __shared__ __align__(16) unsigned short Ks[2][64 * 64];
    __shared__ __align__(16) unsigned short Vs[2][64 * 64];
    __shared__ __align__(16) unsigned short Ps[4][32 * 64];

    const int tid  = threadIdx.x;
    const int w    = tid >> 6;
    const int l    = tid & 63;
    const int lo16 = l & 15;
    const int g    = l >> 4;

    const int q0 = blockIdx.x * 128;
    const int bh = blockIdx.y;
    const int bb = bh >> 4;
    const int hh = bh & 15;

    bf16x8 qf[2][2];
#pragma unroll
    for (int qt = 0; qt < 2; ++qt) {
        const unsigned short* Qp =
            Qh + ((size_t)bh * T_ + q0 + w * 32 + qt * 16 + lo16) * DM_ + g * 8;
        qf[qt][0] = *(const bf16x8*)(Qp);
        qf[qt][1] = *(const bf16x8*)(Qp + 32);
    }

    const unsigned short* Kg0 = Kh + (size_t)bh * T_ * DM_;
    const unsigned short* Vg0 = Vt + (size_t)bh * DM_ * T_;

    const int sro = tid >> 3;
    const int sc8 = tid & 7;
    const int sdst = (sro * 128 + sc8 * 16) ^ ((sro & 7) << 4);

    {
        bf16x8 k0 = *(const bf16x8*)(Kg0 + (size_t)sro * DM_ + sc8 * 8);
        bf16x8 k1 = *(const bf16x8*)(Kg0 + (size_t)(sro + 32) * DM_ + sc8 * 8);
        bf16x8 v0 = *(const bf16x8*)(Vg0 + (size_t)sro * T_ + sc8 * 8);
        bf16x8 v1 = *(const bf16x8*)(Vg0 + (size_t)(sro + 32) * T_ + sc8 * 8);
        *(bf16x8*)((char*)Ks[0] + sdst)        = k0;
        *(bf16x8*)((char*)Ks[0] + sdst + 4096) = k1;
        *(bf16x8*)((char*)Vs[0] + sdst)        = v0;
        *(bf16x8*)((char*)Vs[0] + sdst + 4096) = v1;
    }
    __syncthreads();

    f32x4 oa[2][4] = {};
    float lsum[2] = {0.f, 0.f};
    char* Pb = (char*)&Ps[w][0];

    for (int it = 0; it < T_ / 64; ++it) {
        const int cur = it & 1;
        const char* Kc = (const char*)Ks[cur];
        const char* Vc = (const char*)Vs[cur];
        const bool hn = (it + 1 < T_ / 64);
        bf16x8 nk0, nk1, nv0, nv1;
        if (hn) {
            const unsigned short* Kt  = Kg0 + (size_t)(it + 1) * 64 * DM_;
            const unsigned short* Vt2 = Vg0 + (it + 1) * 64;
            nk0 = *(const bf16x8*)(Kt  + (size_t)sro * DM_ + sc8 * 8);
            nk1 = *(const bf16x8*)(Kt  + (size_t)(sro + 32) * DM_ + sc8 * 8);
            nv0 = *(const bf16x8*)(Vt2 + (size_t)sro * T_ + sc8 * 8);
            nv1 = *(const bf16x8*)(Vt2 + (size_t)(sro + 32) * T_ + sc8 * 8);
        }

        // ---- S^T = K · Q^T
        f32x4 sa[2][4] = {};
        __builtin_amdgcn_s_setprio(1);
#pragma unroll
        for (int ks = 0; ks < 2; ++ks) {
#pragma unroll
            for (int nt = 0; nt < 4; ++nt) {
                int row = nt * 16 + lo16;
                int off = (row * 128 + ks * 64 + g * 16) ^ ((row & 7) << 4);
                bf16x8 kf = *(const bf16x8*)(Kc + off);
#pragma unroll
                for (int qt = 0; qt < 2; ++qt)
                    sa[qt][nt] = __builtin_amdgcn_mfma_f32_16x16x32_bf16(kf, qf[qt][ks], sa[qt][nt], 0, 0, 0);
            }
        }
        __builtin_amdgcn_s_setprio(0);

        // ---- no-max softmax: p = exp2(s + pb); lsum += p; pack -> Ps
        const float* pbp = padb + bb * T_ + it * 64 + g * 4;
        f32x4 pb4[4];
#pragma unroll
        for (int nt = 0; nt < 4; ++nt) pb4[nt] = *(const f32x4*)(pbp + nt * 16);
#pragma unroll
        for (int qt = 0; qt < 2; ++qt) {
            const int prow = qt * 16 + lo16;
            const int rswz = (lo16 & 7) << 4;
#pragma unroll
            for (int nt = 0; nt < 4; ++nt) {
                float e0 = exp2_(sa[qt][nt][0] + pb4[nt][0]);
                float e1 = exp2_(sa[qt][nt][1] + pb4[nt][1]);
                float e2 = exp2_(sa[qt][nt][2] + pb4[nt][2]);
                float e3 = exp2_(sa[qt][nt][3] + pb4[nt][3]);
                lsum[qt] += (e0 + e1) + (e2 + e3);
                uint2 u;
                u.x = pack2bf(e0, e1);
                u.y = pack2bf(e2, e3);
                int wb = (prow * 128 + nt * 32 + g * 8) ^ rswz;
                *(uint2*)(Pb + wb) = u;
            }
        }

        // ---- O^T += V^T · P^T
        __builtin_amdgcn_s_setprio(1);
#pragma unroll
        for (int ks = 0; ks < 2; ++ks) {
            bf16x8 pf[2];
#pragma unroll
            for (int qt = 0; qt < 2; ++qt) {
                int poff = ((qt * 16 + lo16) * 128 + ks * 64 + g * 16) ^ ((lo16 & 7) << 4);
                pf[qt] = *(const bf16x8*)(Pb + poff);
            }
#pragma unroll
            for (int nd = 0; nd < 4; ++nd) {
                int row = nd * 16 + lo16;
                int off = (row * 128 + ks * 64 + g * 16) ^ ((row & 7) << 4);
                bf16x8 vf = *(const bf16x8*)(Vc + off);
#pragma unroll
                for (int qt = 0; qt < 2; ++qt)
                    oa[qt][nd] = __builtin_amdgcn_mfma_f32_16x16x32_bf16(vf, pf[qt], oa[qt][nd], 0, 0, 0);
            }
        }
        __builtin_amdgcn_s_setprio(0);

        if (hn) {
            char* Kd = (char*)Ks[cur ^ 1];
            char* Vd = (char*)Vs[cur ^ 1];
            *(bf16x8*)(Kd + sdst)        = nk0;
            *(bf16x8*)(Kd + sdst + 4096) = nk1;
            *(bf16x8*)(Vd + sdst)        = nv0;
            *(bf16x8*)(Vd + sdst + 4096) = nv1;
        }
        __syncthreads();
    }

    // ---- epilogue: reduce l across g, write ctx
#pragma unroll
    for (int qt = 0; qt < 2; ++qt) {
        float lt = lsum[qt];
        lt += __shfl_xor(lt, 16);
        lt += __shfl_xor(lt, 32);
        float linv = 1.0f / lt;
        const size_t crow =
            ((size_t)(bb * T_ + q0 + w * 32 + qt * 16 + lo16)) * NQ_ + hh * DM_;
#pragma unroll
        for (int nd = 0; nd < 4; ++nd) {
            ushort4 u;
            u.x = f2bf(oa[qt][nd][0] * linv);
            u.y = f2bf(oa[qt][nd][1] * linv);
            u.z = f2bf(oa[qt][nd][2] * linv);
            u.w = f2bf(oa[qt][nd][3] * linv);
            *(ushort4*)&ctx[crow + nd * 16 + g * 4] = u;
        }
    }
}

// ---------------------------------------------------------------------------
extern "C" void kernel_launch(void* const* d_in, const int* in_sizes, int n_in,
                              void* d_out, int out_size, void* d_ws, size_t ws_size,
                              hipStream_t stream) {
    const float* data = (const float*)d_in[0];
    const float* mask = (const float*)d_in[1];
    const float* wq   = (const float*)d_in[2];
    const float* bq   = (const float*)d_in[3];
    const float* wk   = (const float*)d_in[4];
    const float* bk   = (const float*)d_in[5];
    const float* wv   = (const float*)d_in[6];
    const float* bv   = (const float*)d_in[7];
    const float* wo   = (const float*)d_in[8];
    const float* bo   = (const float*)d_in[9];
    float* out = (float*)d_out;

    char* ws = (char*)d_ws;
    const size_t MB = 1024 * 1024;
    unsigned short* Qh    = (unsigned short*)(ws);             // 8MB
    unsigned short* Kh    = (unsigned short*)(ws +  8 * MB);   // 8MB
    unsigned short* Vt    = (unsigned short*)(ws + 16 * MB);   // 8MB
    unsigned short* CTX   = (unsigned short*)(ws + 24 * MB);   // 8MB (bf16)
    unsigned short* dataB = (unsigned short*)(ws + 32 * MB);   // 4MB
    unsigned short* BtAll = (unsigned short*)(ws + 36 * MB);   // 3MB
    unsigned short* wot   = (unsigned short*)(ws + 39 * MB);   // 1MB
    float*          padb  = (float*)         (ws + 40 * MB);   // 16KB

    const int M = B_ * T_;                 // 4096
    const float alpha_q = 0.125f * 1.44269504089f;

    prep_kernel<<<2048, 256, 0, stream>>>(mask, padb, data, dataB);
    {
        dim3 blk(32, 8);
        wtrans_qkv_kernel<<<dim3(NQ_ / 32, D_ / 32, 3), blk, 0, stream>>>(wq, wk, wv, BtAll);
        wtrans_kernel<<<dim3(D_ / 32, NQ_ / 32), blk, 0, stream>>>(wo, wot, NQ_, D_);
    }

    mgemm_qkv_kernel<<<dim3(3 * NQ_ / 128, M / 128), 256, 0, stream>>>(
        dataB, BtAll, bq, bk, bv, Qh, Kh, Vt, alpha_q);

    dim3 gattn(T_ / 128, B_ * H_);
    attn_kernel<<<gattn, 256, 0, stream>>>(Qh, Kh, Vt, padb, CTX);

    mgemm_out_kernel<<<dim3(D_ / 128, M / 64), 256, 0, stream>>>(
        CTX, wot, bo, out, M, D_, NQ_);
}

// Round 6
// 113.949 us; speedup vs baseline: 10.0137x; 1.0100x over previous
//
#include <hip/hip_runtime.h>
#include <hip/hip_bf16.h>

#define B_  2
#define T_  2048
#define D_  512
#define DM_ 64
#define H_  16
#define NQ_ (DM_*H_)   // 1024

typedef __bf16 bf16x8 __attribute__((ext_vector_type(8)));
typedef __bf16 bf16x4 __attribute__((ext_vector_type(4)));
typedef float  f32x4  __attribute__((ext_vector_type(4)));
typedef unsigned int u32;

static __device__ __forceinline__ __bf16 bfc(float x) { return (__bf16)x; }
static __device__ __forceinline__ unsigned short f2bf(float x) {
    __bf16 b = (__bf16)x;
    unsigned short u;
    __builtin_memcpy(&u, &b, 2);
    return u;
}

#if __has_builtin(__builtin_amdgcn_exp2f)
static __device__ __forceinline__ float EXP2(float x) { return __builtin_amdgcn_exp2f(x); }
#else
static __device__ __forceinline__ float EXP2(float x) {
    float r; asm("v_exp_f32 %0, %1\ns_nop 0" : "=v"(r) : "v"(x)); return r;
}
#endif

// async global->LDS, 16B per lane; dest = wave-uniform base + lane*16
#define GLOAD16(gp, lp) \
    __builtin_amdgcn_global_load_lds((const __attribute__((address_space(1))) u32*)(gp), \
                                     (__attribute__((address_space(3))) u32*)(lp), 16, 0, 0)

// ---------------------------------------------------------------------------
// fused prep: [0,1024) pad | [1024,2048) data cvt | [2048,3584) qkv wtrans |
// [3584,4096) wo wtrans
// ---------------------------------------------------------------------------
__global__ __launch_bounds__(256)
void prep_kernel(const float* __restrict__ mask, float* __restrict__ padb,
                 const float* __restrict__ data, unsigned short* __restrict__ dataB,
                 const float* __restrict__ wq, const float* __restrict__ wk,
                 const float* __restrict__ wv, unsigned short* __restrict__ btall,
                 const float* __restrict__ wo, unsigned short* __restrict__ wot)
{
    __shared__ float t[32][33];
    const int bid = blockIdx.x;
    const int tid = threadIdx.x;
    if (bid < 1024) {
        const int row  = bid * 4 + (tid >> 6);
        const int lane = tid & 63;
        const float* p = mask + (size_t)row * D_;
        float4 a = *(const float4*)&p[lane * 8];
        float4 b = *(const float4*)&p[lane * 8 + 4];
        float s = a.x + a.y + a.z + a.w + b.x + b.y + b.z + b.w;
#pragma unroll
        for (int off = 32; off; off >>= 1) s += __shfl_down(s, off);
        if (lane == 0) padb[row] = (s == 0.0f) ? -1e9f : 0.0f;
    } else if (bid < 2048) {
        int i = ((bid - 1024) * 256 + tid) * 8;
        float4 a = *(const float4*)&data[i];
        float4 b = *(const float4*)&data[i + 4];
        bf16x8 u = {bfc(a.x), bfc(a.y), bfc(a.z), bfc(a.w),
                    bfc(b.x), bfc(b.y), bfc(b.z), bfc(b.w)};
        *(bf16x8*)&dataB[i] = u;
    } else if (bid < 3584) {
        const int idx = bid - 2048;
        const int z = idx >> 9, rem = idx & 511;
        const int c0 = (rem & 31) * 32, r0 = (rem >> 5) * 32;   // C=1024, R=512
        const float* in = (z == 0) ? wq : (z == 1) ? wk : wv;
        unsigned short* out = btall + (size_t)z * NQ_ * D_;
        const int tx = tid & 31, ty = tid >> 5;
#pragma unroll
        for (int i = 0; i < 4; ++i)
            t[ty * 4 + i][tx] = in[(size_t)(r0 + ty * 4 + i) * NQ_ + c0 + tx];
        __syncthreads();
#pragma unroll
        for (int i = 0; i < 4; ++i)
            out[(size_t)(c0 + ty * 4 + i) * D_ + r0 + tx] = f2bf(t[tx][ty * 4 + i]);
    } else {
        const int idx = bid - 3584;
        const int c0 = (idx & 15) * 32, r0 = (idx >> 4) * 32;   // C=512, R=1024
        const int tx = tid & 31, ty = tid >> 5;
#pragma unroll
        for (int i = 0; i < 4; ++i)
            t[ty * 4 + i][tx] = wo[(size_t)(r0 + ty * 4 + i) * D_ + c0 + tx];
        __syncthreads();
#pragma unroll
        for (int i = 0; i < 4; ++i)
            wot[(size_t)(c0 + ty * 4 + i) * NQ_ + r0 + tx] = f2bf(t[tx][ty * 4 + i]);
    }
}

// ---------------------------------------------------------------------------
// fused QKV GEMM: A[4096,512] @ BtAll[3072,512]^T, gload_lds dbuf staging.
// seg 0 -> Qh head-major *alpha_q, 1 -> Kh head-major, 2 -> Vt transposed.
// ---------------------------------------------------------------------------
__global__ __launch_bounds__(256)
void mgemm_qkv_kernel(const unsigned short* __restrict__ A,
                      const unsigned short* __restrict__ BtAll,
                      const float* __restrict__ bq, const float* __restrict__ bk,
                      const float* __restrict__ bv,
                      unsigned short* __restrict__ Qh, unsigned short* __restrict__ Kh,
                      unsigned short* __restrict__ Vt, float alpha_q)
{
    const int K = D_;
    __shared__ __align__(16) unsigned short Al[2][128 * 64];
    __shared__ __align__(16) unsigned short Bl[2][128 * 64];

    const int tid = threadIdx.x;
    const int w  = tid >> 6, l = tid & 63;
    const int lo = l & 15,  g = l >> 4;
    const int wri = w >> 1, wci = w & 1;
    const int m0 = blockIdx.y * 128, n0 = blockIdx.x * 128;
    const int lrow = l >> 3;
    const int lslot = (l & 7) ^ lrow;     // pre-swizzled source slot

    f32x4 acc[4][4] = {};
    const int nk = K >> 6;   // 8

    // prologue: stage k-step 0 into buf0
#pragma unroll
    for (int p = 0; p < 4; ++p) {
        int br = w * 32 + p * 8;
        GLOAD16(A     + (size_t)(m0 + br + lrow) * K + lslot * 8, (char*)Al[0] + br * 128);
        GLOAD16(BtAll + (size_t)(n0 + br + lrow) * K + lslot * 8, (char*)Bl[0] + br * 128);
    }
    __syncthreads();

    for (int t = 0; t < nk; ++t) {
        const int cur = t & 1;
        if (t + 1 < nk) {
            const int k0 = (t + 1) << 6;
#pragma unroll
            for (int p = 0; p < 4; ++p) {
                int br = w * 32 + p * 8;
                GLOAD16(A     + (size_t)(m0 + br + lrow) * K + k0 + lslot * 8,
                        (char*)Al[cur ^ 1] + br * 128);
                GLOAD16(BtAll + (size_t)(n0 + br + lrow) * K + k0 + lslot * 8,
                        (char*)Bl[cur ^ 1] + br * 128);
            }
        }
#pragma unroll
        for (int kk = 0; kk < 2; ++kk) {
            bf16x8 af[4], bfr[4];
#pragma unroll
            for (int i = 0; i < 4; ++i) {
                int row = wri * 64 + i * 16 + lo;
                af[i] = *(const bf16x8*)&Al[cur][row * 64 + ((((kk << 2) + g) ^ (row & 7)) << 3)];
                int col = wci * 64 + i * 16 + lo;
                bfr[i] = *(const bf16x8*)&Bl[cur][col * 64 + ((((kk << 2) + g) ^ (col & 7)) << 3)];
            }
#pragma unroll
            for (int i = 0; i < 4; ++i)
#pragma unroll
                for (int j = 0; j < 4; ++j)
                    acc[i][j] = __builtin_amdgcn_mfma_f32_16x16x32_bf16(af[i], bfr[j], acc[i][j], 0, 0, 0);
        }
        __syncthreads();
    }

    const int seg = n0 >> 10;                  // 0:Q 1:K 2:V
    const int n0l = n0 & 1023;
    const float* bias = (seg == 0) ? bq : (seg == 1) ? bk : bv;
    const float alpha = (seg == 0) ? alpha_q : 1.0f;
    unsigned short* o16 = (seg == 0) ? Qh : (seg == 1) ? Kh : Vt;

    const int mb = m0 + wri * 64 + g * 4;
    float bb[4];
#pragma unroll
    for (int j = 0; j < 4; ++j) bb[j] = bias[n0l + wci * 64 + j * 16 + lo];
    const int head = lo;
    const int dmb  = (n0l >> 4) + wci * 4;
    if (seg < 2) {
#pragma unroll
        for (int i = 0; i < 4; ++i)
#pragma unroll
            for (int jj = 0; jj < 4; ++jj) {
                int m = mb + i * 16 + jj;
                int t = m & (T_ - 1), bidx = m >> 11;
                bf16x4 u = {bfc((acc[i][0][jj] + bb[0]) * alpha),
                            bfc((acc[i][1][jj] + bb[1]) * alpha),
                            bfc((acc[i][2][jj] + bb[2]) * alpha),
                            bfc((acc[i][3][jj] + bb[3]) * alpha)};
                *(bf16x4*)&o16[(((size_t)(bidx * H_ + head)) * T_ + t) * DM_ + dmb] = u;
            }
    } else {
#pragma unroll
        for (int i = 0; i < 4; ++i)
#pragma unroll
            for (int j = 0; j < 4; ++j) {
                int m = mb + i * 16;
                int t = m & (T_ - 1), bidx = m >> 11;
                bf16x4 u = {bfc(acc[i][j][0] + bb[j]), bfc(acc[i][j][1] + bb[j]),
                            bfc(acc[i][j][2] + bb[j]), bfc(acc[i][j][3] + bb[j])};
                *(bf16x4*)&o16[((size_t)(bidx * H_ + head) * DM_ + dmb + j) * T_ + t] = u;
            }
    }
}

// ---------------------------------------------------------------------------
// out-projection GEMM (fp32 out), 64x128 tile, gload_lds dbuf staging.
// ---------------------------------------------------------------------------
__global__ __launch_bounds__(256)
void mgemm_out_kernel(const unsigned short* __restrict__ A,
                      const unsigned short* __restrict__ Bt,
                      const float* __restrict__ bias, float* __restrict__ out,
                      int M, int N, int K)
{
    __shared__ __align__(16) unsigned short Al[2][64 * 64];
    __shared__ __align__(16) unsigned short Bl[2][128 * 64];

    const int tid = threadIdx.x;
    const int w  = tid >> 6, l = tid & 63;
    const int lo = l & 15,  g = l >> 4;
    const int wri = w >> 1, wci = w & 1;
    const int m0 = blockIdx.y * 64, n0 = blockIdx.x * 128;
    const int lrow = l >> 3;
    const int lslot = (l & 7) ^ lrow;

    f32x4 acc[2][4] = {};
    const int nk = K >> 6;

#pragma unroll
    for (int p = 0; p < 2; ++p) {
        int br = w * 16 + p * 8;
        GLOAD16(A + (size_t)(m0 + br + lrow) * K + lslot * 8, (char*)Al[0] + br * 128);
    }
#pragma unroll
    for (int p = 0; p < 4; ++p) {
        int br = w * 32 + p * 8;
        GLOAD16(Bt + (size_t)(n0 + br + lrow) * K + lslot * 8, (char*)Bl[0] + br * 128);
    }
    __syncthreads();

    for (int t = 0; t < nk; ++t) {
        const int cur = t & 1;
        if (t + 1 < nk) {
            const int k0 = (t + 1) << 6;
#pragma unroll
            for (int p = 0; p < 2; ++p) {
                int br = w * 16 + p * 8;
                GLOAD16(A + (size_t)(m0 + br + lrow) * K + k0 + lslot * 8,
                        (char*)Al[cur ^ 1] + br * 128);
            }
#pragma unroll
            for (int p = 0; p < 4; ++p) {
                int br = w * 32 + p * 8;
                GLOAD16(Bt + (size_t)(n0 + br + lrow) * K + k0 + lslot * 8,
                        (char*)Bl[cur ^ 1] + br * 128);
            }
        }
#pragma unroll
        for (int kk = 0; kk < 2; ++kk) {
            bf16x8 af[2], bfr[4];
#pragma unroll
            for (int i = 0; i < 2; ++i) {
                int row = wri * 32 + i * 16 + lo;
                af[i] = *(const bf16x8*)&Al[cur][row * 64 + ((((kk << 2) + g) ^ (row & 7)) << 3)];
            }
#pragma unroll
            for (int j = 0; j < 4; ++j) {
                int col = wci * 64 + j * 16 + lo;
                bfr[j] = *(const bf16x8*)&Bl[cur][col * 64 + ((((kk << 2) + g) ^ (col & 7)) << 3)];
            }
#pragma unroll
            for (int i = 0; i < 2; ++i)
#pragma unroll
                for (int j = 0; j < 4; ++j)
                    acc[i][j] = __builtin_amdgcn_mfma_f32_16x16x32_bf16(af[i], bfr[j], acc[i][j], 0, 0, 0);
        }
        __syncthreads();
    }

    const int mb = m0 + wri * 32 + g * 4;
#pragma unroll
    for (int j = 0; j < 4; ++j) {
        int n = n0 + wci * 64 + j * 16 + lo;
        float bb = bias[n];
#pragma unroll
        for (int i = 0; i < 2; ++i)
#pragma unroll
            for (int jj = 0; jj < 4; ++jj) {
                int m = mb + i * 16 + jj;
                out[(size_t)m * N + n] = acc[i][j][jj] + bb;
            }
    }
}

// ---------------------------------------------------------------------------
// MFMA flash attention: no-max softmax, pad bias via MFMA C-init,
// gload_lds dbuf K/V staging, native exp2 + cvt_pk, QBLK=128.
// ---------------------------------------------------------------------------
__global__ __launch_bounds__(256, 3)
void attn_kernel(const unsigned short* __restrict__ Qh,
                 const unsigned short* __restrict__ Kh,
                 const unsigned short* __restrict__ Vt,
                 const float* __restrict__ padb,
                 unsigned short* __restrict__ ctx)
{
    __shared__ __align__(16) unsigned short Ks[2][64 * 64];
    __shared__ __align__(16) unsigned short Vs[2][64 * 64];
    __shared__ __align__(16) unsigned short Ps[4][32 * 64];
    __shared__ __align__(16) float pbs[T_];

    const int tid  = threadIdx.x;
    const int w    = tid >> 6;
    const int l    = tid & 63;
    const int lo16 = l & 15;
    const int g    = l >> 4;
    const int lrow = l >> 3;
    const int lslot = (l & 7) ^ lrow;

    const int q0 = blockIdx.x * 128;
    const int bh = blockIdx.y;
    const int bb = bh >> 4;
    const int hh = bh & 15;

    bf16x8 qf[2][2];
#pragma unroll
    for (int qt = 0; qt < 2; ++qt) {
        const unsigned short* Qp =
            Qh + ((size_t)bh * T_ + q0 + w * 32 + qt * 16 + lo16) * DM_ + g * 8;
        qf[qt][0] = *(const bf16x8*)(Qp);
        qf[qt][1] = *(const bf16x8*)(Qp + 32);
    }

    const unsigned short* Kg0 = Kh + (size_t)bh * T_ * DM_;
    const unsigned short* Vg0 = Vt + (size_t)bh * DM_ * T_;

    // pad-bias table -> LDS (whole key range for this batch)
    {
        const float* src = padb + bb * T_ + tid * 8;
        *(float4*)&pbs[tid * 8]     = *(const float4*)(src);
        *(float4*)&pbs[tid * 8 + 4] = *(const float4*)(src + 4);
    }
    // stage tile 0 -> buf 0
#pragma unroll
    for (int p = 0; p < 2; ++p) {
        int br = w * 16 + p * 8;
        GLOAD16(Kg0 + (size_t)(br + lrow) * DM_ + lslot * 8, (char*)Ks[0] + br * 128);
        GLOAD16(Vg0 + (size_t)(br + lrow) * T_ + lslot * 8, (char*)Vs[0] + br * 128);
    }
    __syncthreads();

    f32x4 oa[2][4] = {};
    f32x4 ls4[2] = {};
    char* Pb = (char*)&Ps[w][0];

    for (int it = 0; it < T_ / 64; ++it) {
        const int cur = it & 1;
        const char* Kc = (const char*)Ks[cur];
        const char* Vc = (const char*)Vs[cur];
        if (it + 1 < T_ / 64) {
            const int ktn = (it + 1) * 64;
#pragma unroll
            for (int p = 0; p < 2; ++p) {
                int br = w * 16 + p * 8;
                GLOAD16(Kg0 + (size_t)(ktn + br + lrow) * DM_ + lslot * 8,
                        (char*)Ks[cur ^ 1] + br * 128);
                GLOAD16(Vg0 + (size_t)(br + lrow) * T_ + ktn + lslot * 8,
                        (char*)Vs[cur ^ 1] + br * 128);
            }
        }

        // ---- S^T = K · Q^T, C-init = pad bias (key-indexed)
        f32x4 sa[2][4];
#pragma unroll
        for (int nt = 0; nt < 4; ++nt) {
            f32x4 pb4 = *(const f32x4*)&pbs[it * 64 + nt * 16 + g * 4];
            sa[0][nt] = pb4;
            sa[1][nt] = pb4;
        }
        __builtin_amdgcn_s_setprio(1);
#pragma unroll
        for (int ks = 0; ks < 2; ++ks) {
#pragma unroll
            for (int nt = 0; nt < 4; ++nt) {
                int row = nt * 16 + lo16;
                int off = (row * 128 + ks * 64 + g * 16) ^ ((row & 7) << 4);
                bf16x8 kf = *(const bf16x8*)(Kc + off);
#pragma unroll
                for (int qt = 0; qt < 2; ++qt)
                    sa[qt][nt] = __builtin_amdgcn_mfma_f32_16x16x32_bf16(kf, qf[qt][ks], sa[qt][nt], 0, 0, 0);
            }
        }
        __builtin_amdgcn_s_setprio(0);

        // ---- p = exp2(s); lsum += p; pack bf16 -> Ps
#pragma unroll
        for (int qt = 0; qt < 2; ++qt) {
            const int prow = qt * 16 + lo16;
            const int rswz = (lo16 & 7) << 4;
#pragma unroll
            for (int nt = 0; nt < 4; ++nt) {
                float e0 = EXP2(sa[qt][nt][0]);
                float e1 = EXP2(sa[qt][nt][1]);
                float e2 = EXP2(sa[qt][nt][2]);
                float e3 = EXP2(sa[qt][nt][3]);
                ls4[qt] += (f32x4){e0, e1, e2, e3};
                bf16x4 pv4 = {bfc(e0), bfc(e1), bfc(e2), bfc(e3)};
                int wb = (prow * 128 + nt * 32 + g * 8) ^ rswz;
                *(bf16x4*)(Pb + wb) = pv4;
            }
        }

        // ---- O^T += V^T · P^T
        __builtin_amdgcn_s_setprio(1);
#pragma unroll
        for (int ks = 0; ks < 2; ++ks) {
            bf16x8 pf[2];
#pragma unroll
            for (int qt = 0; qt < 2; ++qt) {
                int poff = ((qt * 16 + lo16) * 128 + ks * 64 + g * 16) ^ ((lo16 & 7) << 4);
                pf[qt] = *(const bf16x8*)(Pb + poff);
            }
#pragma unroll
            for (int nd = 0; nd < 4; ++nd) {
                int row = nd * 16 + lo16;
                int off = (row * 128 + ks * 64 + g * 16) ^ ((row & 7) << 4);
                bf16x8 vf = *(const bf16x8*)(Vc + off);
#pragma unroll
                for (int qt = 0; qt < 2; ++qt)
                    oa[qt][nd] = __builtin_amdgcn_mfma_f32_16x16x32_bf16(vf, pf[qt], oa[qt][nd], 0, 0, 0);
            }
        }
        __builtin_amdgcn_s_setprio(0);

        __syncthreads();
    }

    // ---- epilogue
#pragma unroll
    for (int qt = 0; qt < 2; ++qt) {
        float lt = (ls4[qt][0] + ls4[qt][1]) + (ls4[qt][2] + ls4[qt][3]);
        lt += __shfl_xor(lt, 16);
        lt += __shfl_xor(lt, 32);
        float linv = 1.0f / lt;
        const size_t crow =
            ((size_t)(bb * T_ + q0 + w * 32 + qt * 16 + lo16)) * NQ_ + hh * DM_;
#pragma unroll
        for (int nd = 0; nd < 4; ++nd) {
            bf16x4 u = {bfc(oa[qt][nd][0] * linv), bfc(oa[qt][nd][1] * linv),
                        bfc(oa[qt][nd][2] * linv), bfc(oa[qt][nd][3] * linv)};
            *(bf16x4*)&ctx[crow + nd * 16 + g * 4] = u;
        }
    }
}

// ---------------------------------------------------------------------------
extern "C" void kernel_launch(void* const* d_in, const int* in_sizes, int n_in,
                              void* d_out, int out_size, void* d_ws, size_t ws_size,
                              hipStream_t stream) {
    const float* data = (const float*)d_in[0];
    const float* mask = (const float*)d_in[1];
    const float* wq   = (const float*)d_in[2];
    const float* bq   = (const float*)d_in[3];
    const float* wk   = (const float*)d_in[4];
    const float* bk   = (const float*)d_in[5];
    const float* wv   = (const float*)d_in[6];
    const float* bv   = (const float*)d_in[7];
    const float* wo   = (const float*)d_in[8];
    const float* bo   = (const float*)d_in[9];
    float* out = (float*)d_out;

    char* ws = (char*)d_ws;
    const size_t MB = 1024 * 1024;
    unsigned short* Qh    = (unsigned short*)(ws);             // 8MB
    unsigned short* Kh    = (unsigned short*)(ws +  8 * MB);   // 8MB
    unsigned short* Vt    = (unsigned short*)(ws + 16 * MB);   // 8MB
    unsigned short* CTX   = (unsigned short*)(ws + 24 * MB);   // 8MB (bf16)
    unsigned short* dataB = (unsigned short*)(ws + 32 * MB);   // 4MB
    unsigned short* BtAll = (unsigned short*)(ws + 36 * MB);   // 3MB
    unsigned short* wot   = (unsigned short*)(ws + 39 * MB);   // 1MB
    float*          padb  = (float*)         (ws + 40 * MB);   // 16KB

    const int M = B_ * T_;                 // 4096
    const float alpha_q = 0.125f * 1.44269504089f;

    prep_kernel<<<4096, 256, 0, stream>>>(mask, padb, data, dataB,
                                          wq, wk, wv, BtAll, wo, wot);

    mgemm_qkv_kernel<<<dim3(3 * NQ_ / 128, M / 128), 256, 0, stream>>>(
        dataB, BtAll, bq, bk, bv, Qh, Kh, Vt, alpha_q);

    dim3 gattn(T_ / 128, B_ * H_);
    attn_kernel<<<gattn, 256, 0, stream>>>(Qh, Kh, Vt, padb, CTX);

    mgemm_out_kernel<<<dim3(D_ / 128, M / 64), 256, 0, stream>>>(
        CTX, wot, bo, out, M, D_, NQ_);
}

// Round 7
// 105.373 us; speedup vs baseline: 10.8287x; 1.0814x over previous
//
#include <hip/hip_runtime.h>
#include <hip/hip_bf16.h>

#define B_  2
#define T_  2048
#define D_  512
#define DM_ 64
#define H_  16
#define NQ_ (DM_*H_)   // 1024

typedef __bf16 bf16x8 __attribute__((ext_vector_type(8)));
typedef __bf16 bf16x4 __attribute__((ext_vector_type(4)));
typedef float  f32x4  __attribute__((ext_vector_type(4)));
typedef unsigned int u32;

static __device__ __forceinline__ __bf16 bfc(float x) { return (__bf16)x; }
static __device__ __forceinline__ unsigned short f2bf(float x) {
    __bf16 b = (__bf16)x;
    unsigned short u;
    __builtin_memcpy(&u, &b, 2);
    return u;
}

#if __has_builtin(__builtin_amdgcn_exp2f)
static __device__ __forceinline__ float EXP2(float x) { return __builtin_amdgcn_exp2f(x); }
#else
static __device__ __forceinline__ float EXP2(float x) {
    float r; asm("v_exp_f32 %0, %1\ns_nop 0" : "=v"(r) : "v"(x)); return r;
}
#endif

// async global->LDS, 16B per lane; dest = wave-uniform base + lane*16
#define GLOAD16(gp, lp) \
    __builtin_amdgcn_global_load_lds((const __attribute__((address_space(1))) u32*)(gp), \
                                     (__attribute__((address_space(3))) u32*)(lp), 16, 0, 0)

// ---------------------------------------------------------------------------
// fused prep: [0,1024) pad | [1024,2048) data cvt | [2048,3584) qkv wtrans |
// [3584,4096) wo wtrans
// ---------------------------------------------------------------------------
__global__ __launch_bounds__(256)
void prep_kernel(const float* __restrict__ mask, float* __restrict__ padb,
                 const float* __restrict__ data, unsigned short* __restrict__ dataB,
                 const float* __restrict__ wq, const float* __restrict__ wk,
                 const float* __restrict__ wv, unsigned short* __restrict__ btall,
                 const float* __restrict__ wo, unsigned short* __restrict__ wot)
{
    __shared__ float t[32][33];
    const int bid = blockIdx.x;
    const int tid = threadIdx.x;
    if (bid < 1024) {
        const int row  = bid * 4 + (tid >> 6);
        const int lane = tid & 63;
        const float* p = mask + (size_t)row * D_;
        float4 a = *(const float4*)&p[lane * 8];
        float4 b = *(const float4*)&p[lane * 8 + 4];
        float s = a.x + a.y + a.z + a.w + b.x + b.y + b.z + b.w;
#pragma unroll
        for (int off = 32; off; off >>= 1) s += __shfl_down(s, off);
        if (lane == 0) padb[row] = (s == 0.0f) ? -1e9f : 0.0f;
    } else if (bid < 2048) {
        int i = ((bid - 1024) * 256 + tid) * 8;
        float4 a = *(const float4*)&data[i];
        float4 b = *(const float4*)&data[i + 4];
        bf16x8 u = {bfc(a.x), bfc(a.y), bfc(a.z), bfc(a.w),
                    bfc(b.x), bfc(b.y), bfc(b.z), bfc(b.w)};
        *(bf16x8*)&dataB[i] = u;
    } else if (bid < 3584) {
        const int idx = bid - 2048;
        const int z = idx >> 9, rem = idx & 511;
        const int c0 = (rem & 31) * 32, r0 = (rem >> 5) * 32;   // C=1024, R=512
        const float* in = (z == 0) ? wq : (z == 1) ? wk : wv;
        unsigned short* out = btall + (size_t)z * NQ_ * D_;
        const int tx = tid & 31, ty = tid >> 5;
#pragma unroll
        for (int i = 0; i < 4; ++i)
            t[ty * 4 + i][tx] = in[(size_t)(r0 + ty * 4 + i) * NQ_ + c0 + tx];
        __syncthreads();
#pragma unroll
        for (int i = 0; i < 4; ++i)
            out[(size_t)(c0 + ty * 4 + i) * D_ + r0 + tx] = f2bf(t[tx][ty * 4 + i]);
    } else {
        const int idx = bid - 3584;
        const int c0 = (idx & 15) * 32, r0 = (idx >> 4) * 32;   // C=512, R=1024
        const int tx = tid & 31, ty = tid >> 5;
#pragma unroll
        for (int i = 0; i < 4; ++i)
            t[ty * 4 + i][tx] = wo[(size_t)(r0 + ty * 4 + i) * D_ + c0 + tx];
        __syncthreads();
#pragma unroll
        for (int i = 0; i < 4; ++i)
            wot[(size_t)(c0 + ty * 4 + i) * NQ_ + r0 + tx] = f2bf(t[tx][ty * 4 + i]);
    }
}

// ---------------------------------------------------------------------------
// fused QKV GEMM: A[4096,512] @ BtAll[3072,512]^T, gload_lds dbuf staging.
// seg 0 -> Qh head-major *alpha_q, 1 -> Kh head-major, 2 -> Vt transposed.
// ---------------------------------------------------------------------------
__global__ __launch_bounds__(256)
void mgemm_qkv_kernel(const unsigned short* __restrict__ A,
                      const unsigned short* __restrict__ BtAll,
                      const float* __restrict__ bq, const float* __restrict__ bk,
                      const float* __restrict__ bv,
                      unsigned short* __restrict__ Qh, unsigned short* __restrict__ Kh,
                      unsigned short* __restrict__ Vt, float alpha_q)
{
    const int K = D_;
    __shared__ __align__(16) unsigned short Al[2][128 * 64];
    __shared__ __align__(16) unsigned short Bl[2][128 * 64];

    const int tid = threadIdx.x;
    const int w  = tid >> 6, l = tid & 63;
    const int lo = l & 15,  g = l >> 4;
    const int wri = w >> 1, wci = w & 1;
    const int m0 = blockIdx.y * 128, n0 = blockIdx.x * 128;
    const int lrow = l >> 3;
    const int lslot = (l & 7) ^ lrow;     // pre-swizzled source slot

    f32x4 acc[4][4] = {};
    const int nk = K >> 6;   // 8

    // prologue: stage k-step 0 into buf0
#pragma unroll
    for (int p = 0; p < 4; ++p) {
        int br = w * 32 + p * 8;
        GLOAD16(A     + (size_t)(m0 + br + lrow) * K + lslot * 8, (char*)Al[0] + br * 128);
        GLOAD16(BtAll + (size_t)(n0 + br + lrow) * K + lslot * 8, (char*)Bl[0] + br * 128);
    }
    __syncthreads();

    for (int t = 0; t < nk; ++t) {
        const int cur = t & 1;
        if (t + 1 < nk) {
            const int k0 = (t + 1) << 6;
#pragma unroll
            for (int p = 0; p < 4; ++p) {
                int br = w * 32 + p * 8;
                GLOAD16(A     + (size_t)(m0 + br + lrow) * K + k0 + lslot * 8,
                        (char*)Al[cur ^ 1] + br * 128);
                GLOAD16(BtAll + (size_t)(n0 + br + lrow) * K + k0 + lslot * 8,
                        (char*)Bl[cur ^ 1] + br * 128);
            }
        }
#pragma unroll
        for (int kk = 0; kk < 2; ++kk) {
            bf16x8 af[4], bfr[4];
#pragma unroll
            for (int i = 0; i < 4; ++i) {
                int row = wri * 64 + i * 16 + lo;
                af[i] = *(const bf16x8*)&Al[cur][row * 64 + ((((kk << 2) + g) ^ (row & 7)) << 3)];
                int col = wci * 64 + i * 16 + lo;
                bfr[i] = *(const bf16x8*)&Bl[cur][col * 64 + ((((kk << 2) + g) ^ (col & 7)) << 3)];
            }
#pragma unroll
            for (int i = 0; i < 4; ++i)
#pragma unroll
                for (int j = 0; j < 4; ++j)
                    acc[i][j] = __builtin_amdgcn_mfma_f32_16x16x32_bf16(af[i], bfr[j], acc[i][j], 0, 0, 0);
        }
        __syncthreads();
    }

    const int seg = n0 >> 10;                  // 0:Q 1:K 2:V
    const int n0l = n0 & 1023;
    const float* bias = (seg == 0) ? bq : (seg == 1) ? bk : bv;
    const float alpha = (seg == 0) ? alpha_q : 1.0f;
    unsigned short* o16 = (seg == 0) ? Qh : (seg == 1) ? Kh : Vt;

    const int mb = m0 + wri * 64 + g * 4;
    float bb[4];
#pragma unroll
    for (int j = 0; j < 4; ++j) bb[j] = bias[n0l + wci * 64 + j * 16 + lo];
    const int head = lo;
    const int dmb  = (n0l >> 4) + wci * 4;
    if (seg < 2) {
#pragma unroll
        for (int i = 0; i < 4; ++i)
#pragma unroll
            for (int jj = 0; jj < 4; ++jj) {
                int m = mb + i * 16 + jj;
                int t = m & (T_ - 1), bidx = m >> 11;
                bf16x4 u = {bfc((acc[i][0][jj] + bb[0]) * alpha),
                            bfc((acc[i][1][jj] + bb[1]) * alpha),
                            bfc((acc[i][2][jj] + bb[2]) * alpha),
                            bfc((acc[i][3][jj] + bb[3]) * alpha)};
                *(bf16x4*)&o16[(((size_t)(bidx * H_ + head)) * T_ + t) * DM_ + dmb] = u;
            }
    } else {
#pragma unroll
        for (int i = 0; i < 4; ++i)
#pragma unroll
            for (int j = 0; j < 4; ++j) {
                int m = mb + i * 16;
                int t = m & (T_ - 1), bidx = m >> 11;
                bf16x4 u = {bfc(acc[i][j][0] + bb[j]), bfc(acc[i][j][1] + bb[j]),
                            bfc(acc[i][j][2] + bb[j]), bfc(acc[i][j][3] + bb[j])};
                *(bf16x4*)&o16[((size_t)(bidx * H_ + head) * DM_ + dmb + j) * T_ + t] = u;
            }
    }
}

// ---------------------------------------------------------------------------
// out-projection GEMM (fp32 out), 64x128 tile, gload_lds dbuf staging.
// ---------------------------------------------------------------------------
__global__ __launch_bounds__(256)
void mgemm_out_kernel(const unsigned short* __restrict__ A,
                      const unsigned short* __restrict__ Bt,
                      const float* __restrict__ bias, float* __restrict__ out,
                      int M, int N, int K)
{
    __shared__ __align__(16) unsigned short Al[2][64 * 64];
    __shared__ __align__(16) unsigned short Bl[2][128 * 64];

    const int tid = threadIdx.x;
    const int w  = tid >> 6, l = tid & 63;
    const int lo = l & 15,  g = l >> 4;
    const int wri = w >> 1, wci = w & 1;
    const int m0 = blockIdx.y * 64, n0 = blockIdx.x * 128;
    const int lrow = l >> 3;
    const int lslot = (l & 7) ^ lrow;

    f32x4 acc[2][4] = {};
    const int nk = K >> 6;

#pragma unroll
    for (int p = 0; p < 2; ++p) {
        int br = w * 16 + p * 8;
        GLOAD16(A + (size_t)(m0 + br + lrow) * K + lslot * 8, (char*)Al[0] + br * 128);
    }
#pragma unroll
    for (int p = 0; p < 4; ++p) {
        int br = w * 32 + p * 8;
        GLOAD16(Bt + (size_t)(n0 + br + lrow) * K + lslot * 8, (char*)Bl[0] + br * 128);
    }
    __syncthreads();

    for (int t = 0; t < nk; ++t) {
        const int cur = t & 1;
        if (t + 1 < nk) {
            const int k0 = (t + 1) << 6;
#pragma unroll
            for (int p = 0; p < 2; ++p) {
                int br = w * 16 + p * 8;
                GLOAD16(A + (size_t)(m0 + br + lrow) * K + k0 + lslot * 8,
                        (char*)Al[cur ^ 1] + br * 128);
            }
#pragma unroll
            for (int p = 0; p < 4; ++p) {
                int br = w * 32 + p * 8;
                GLOAD16(Bt + (size_t)(n0 + br + lrow) * K + k0 + lslot * 8,
                        (char*)Bl[cur ^ 1] + br * 128);
            }
        }
#pragma unroll
        for (int kk = 0; kk < 2; ++kk) {
            bf16x8 af[2], bfr[4];
#pragma unroll
            for (int i = 0; i < 2; ++i) {
                int row = wri * 32 + i * 16 + lo;
                af[i] = *(const bf16x8*)&Al[cur][row * 64 + ((((kk << 2) + g) ^ (row & 7)) << 3)];
            }
#pragma unroll
            for (int j = 0; j < 4; ++j) {
                int col = wci * 64 + j * 16 + lo;
                bfr[j] = *(const bf16x8*)&Bl[cur][col * 64 + ((((kk << 2) + g) ^ (col & 7)) << 3)];
            }
#pragma unroll
            for (int i = 0; i < 2; ++i)
#pragma unroll
                for (int j = 0; j < 4; ++j)
                    acc[i][j] = __builtin_amdgcn_mfma_f32_16x16x32_bf16(af[i], bfr[j], acc[i][j], 0, 0, 0);
        }
        __syncthreads();
    }

    const int mb = m0 + wri * 32 + g * 4;
#pragma unroll
    for (int j = 0; j < 4; ++j) {
        int n = n0 + wci * 64 + j * 16 + lo;
        float bb = bias[n];
#pragma unroll
        for (int i = 0; i < 2; ++i)
#pragma unroll
            for (int jj = 0; jj < 4; ++jj) {
                int m = mb + i * 16 + jj;
                out[(size_t)m * N + n] = acc[i][j][jj] + bb;
            }
    }
}

// ---------------------------------------------------------------------------
// MFMA flash attention v7: 8 waves/block (512 thr), 16 q/wave, QBLK=128,
// KVBLK=64 dbuf via gload_lds, no-max softmax, pad bias as MFMA C-init,
// XCD-aware 1-D grid (blocks sharing a head cluster on one XCD's L2).
// ---------------------------------------------------------------------------
__global__ __launch_bounds__(512, 4)
void attn_kernel(const unsigned short* __restrict__ Qh,
                 const unsigned short* __restrict__ Kh,
                 const unsigned short* __restrict__ Vt,
                 const float* __restrict__ padb,
                 unsigned short* __restrict__ ctx)
{
    __shared__ __align__(16) unsigned short Ks[2][64 * 64];
    __shared__ __align__(16) unsigned short Vs[2][64 * 64];
    __shared__ __align__(16) unsigned short Ps[8][16 * 64];

    const int tid  = threadIdx.x;
    const int w    = tid >> 6;        // 0..7
    const int l    = tid & 63;
    const int lo16 = l & 15;
    const int g    = l >> 4;
    const int lrow = l >> 3;          // 0..7
    const int lslot = (l & 7) ^ lrow; // pre-swizzled source slot

    // XCD-aware decode: f%8 = XCD (round-robin dispatch); 16 q-blocks of a
    // head stay on one XCD -> K/V (512KB/head, 2MB per XCD group) L2-resident.
    const int f   = blockIdx.x;
    const int s   = f >> 3;
    const int bh  = (f & 7) * 4 + (s >> 4);
    const int q0  = (s & 15) * 128;
    const int bb  = bh >> 4;
    const int hh  = bh & 15;

    bf16x8 qf[2];
    {
        const unsigned short* Qp =
            Qh + ((size_t)bh * T_ + q0 + w * 16 + lo16) * DM_ + g * 8;
        qf[0] = *(const bf16x8*)(Qp);
        qf[1] = *(const bf16x8*)(Qp + 32);
    }

    const unsigned short* Kg0 = Kh + (size_t)bh * T_ * DM_;
    const unsigned short* Vg0 = Vt + (size_t)bh * DM_ * T_;
    const float* pbase = padb + bb * T_;

    // stage tile 0 -> buf 0: wave w covers rows w*8 .. w*8+7 (1KB per wave)
    GLOAD16(Kg0 + (size_t)(w * 8 + lrow) * DM_ + lslot * 8, (char*)Ks[0] + w * 1024);
    GLOAD16(Vg0 + (size_t)(w * 8 + lrow) * T_ + lslot * 8, (char*)Vs[0] + w * 1024);
    __syncthreads();

    f32x4 oa[4] = {};
    f32x4 ls4 = {};
    char* Pb = (char*)&Ps[w][0];
    const int rswz = (lo16 & 7) << 4;

    for (int it = 0; it < T_ / 64; ++it) {
        const int cur = it & 1;
        const char* Kc = (const char*)Ks[cur];
        const char* Vc = (const char*)Vs[cur];
        if (it + 1 < T_ / 64) {
            const int ktn = (it + 1) * 64;
            GLOAD16(Kg0 + (size_t)(ktn + w * 8 + lrow) * DM_ + lslot * 8,
                    (char*)Ks[cur ^ 1] + w * 1024);
            GLOAD16(Vg0 + (size_t)(w * 8 + lrow) * T_ + ktn + lslot * 8,
                    (char*)Vs[cur ^ 1] + w * 1024);
        }

        // ---- S^T = K · Q^T, C-init = pad bias (key-indexed)
        f32x4 sa[4];
#pragma unroll
        for (int nt = 0; nt < 4; ++nt)
            sa[nt] = *(const f32x4*)&pbase[it * 64 + nt * 16 + g * 4];
        __builtin_amdgcn_s_setprio(1);
#pragma unroll
        for (int ks = 0; ks < 2; ++ks) {
#pragma unroll
            for (int nt = 0; nt < 4; ++nt) {
                int row = nt * 16 + lo16;
                int off = (row * 128 + ks * 64 + g * 16) ^ ((row & 7) << 4);
                bf16x8 kf = *(const bf16x8*)(Kc + off);
                sa[nt] = __builtin_amdgcn_mfma_f32_16x16x32_bf16(kf, qf[ks], sa[nt], 0, 0, 0);
            }
        }
        __builtin_amdgcn_s_setprio(0);

        // ---- p = exp2(s); lsum += p; pack bf16 -> Ps (per-wave, swizzled)
#pragma unroll
        for (int nt = 0; nt < 4; ++nt) {
            float e0 = EXP2(sa[nt][0]);
            float e1 = EXP2(sa[nt][1]);
            float e2 = EXP2(sa[nt][2]);
            float e3 = EXP2(sa[nt][3]);
            ls4 += (f32x4){e0, e1, e2, e3};
            bf16x4 pv4 = {bfc(e0), bfc(e1), bfc(e2), bfc(e3)};
            int wb = (lo16 * 128 + nt * 32 + g * 8) ^ rswz;
            *(bf16x4*)(Pb + wb) = pv4;
        }

        // ---- O^T += V^T · P^T
        __builtin_amdgcn_s_setprio(1);
#pragma unroll
        for (int ks = 0; ks < 2; ++ks) {
            int poff = (lo16 * 128 + ks * 64 + g * 16) ^ rswz;
            bf16x8 pf = *(const bf16x8*)(Pb + poff);
#pragma unroll
            for (int nd = 0; nd < 4; ++nd) {
                int row = nd * 16 + lo16;
                int off = (row * 128 + ks * 64 + g * 16) ^ ((row & 7) << 4);
                bf16x8 vf = *(const bf16x8*)(Vc + off);
                oa[nd] = __builtin_amdgcn_mfma_f32_16x16x32_bf16(vf, pf, oa[nd], 0, 0, 0);
            }
        }
        __builtin_amdgcn_s_setprio(0);

        __syncthreads();
    }

    // ---- epilogue: reduce l across g, write ctx
    float lt = (ls4[0] + ls4[1]) + (ls4[2] + ls4[3]);
    lt += __shfl_xor(lt, 16);
    lt += __shfl_xor(lt, 32);
    float linv = 1.0f / lt;
    const size_t crow =
        ((size_t)(bb * T_ + q0 + w * 16 + lo16)) * NQ_ + hh * DM_;
#pragma unroll
    for (int nd = 0; nd < 4; ++nd) {
        bf16x4 u = {bfc(oa[nd][0] * linv), bfc(oa[nd][1] * linv),
                    bfc(oa[nd][2] * linv), bfc(oa[nd][3] * linv)};
        *(bf16x4*)&ctx[crow + nd * 16 + g * 4] = u;
    }
}

// ---------------------------------------------------------------------------
extern "C" void kernel_launch(void* const* d_in, const int* in_sizes, int n_in,
                              void* d_out, int out_size, void* d_ws, size_t ws_size,
                              hipStream_t stream) {
    const float* data = (const float*)d_in[0];
    const float* mask = (const float*)d_in[1];
    const float* wq   = (const float*)d_in[2];
    const float* bq   = (const float*)d_in[3];
    const float* wk   = (const float*)d_in[4];
    const float* bk   = (const float*)d_in[5];
    const float* wv   = (const float*)d_in[6];
    const float* bv   = (const float*)d_in[7];
    const float* wo   = (const float*)d_in[8];
    const float* bo   = (const float*)d_in[9];
    float* out = (float*)d_out;

    char* ws = (char*)d_ws;
    const size_t MB = 1024 * 1024;
    unsigned short* Qh    = (unsigned short*)(ws);             // 8MB
    unsigned short* Kh    = (unsigned short*)(ws +  8 * MB);   // 8MB
    unsigned short* Vt    = (unsigned short*)(ws + 16 * MB);   // 8MB
    unsigned short* CTX   = (unsigned short*)(ws + 24 * MB);   // 8MB (bf16)
    unsigned short* dataB = (unsigned short*)(ws + 32 * MB);   // 4MB
    unsigned short* BtAll = (unsigned short*)(ws + 36 * MB);   // 3MB
    unsigned short* wot   = (unsigned short*)(ws + 39 * MB);   // 1MB
    float*          padb  = (float*)         (ws + 40 * MB);   // 16KB

    const int M = B_ * T_;                 // 4096
    const float alpha_q = 0.125f * 1.44269504089f;

    prep_kernel<<<4096, 256, 0, stream>>>(mask, padb, data, dataB,
                                          wq, wk, wv, BtAll, wo, wot);

    mgemm_qkv_kernel<<<dim3(3 * NQ_ / 128, M / 128), 256, 0, stream>>>(
        dataB, BtAll, bq, bk, bv, Qh, Kh, Vt, alpha_q);

    attn_kernel<<<512, 512, 0, stream>>>(Qh, Kh, Vt, padb, CTX);

    mgemm_out_kernel<<<dim3(D_ / 128, M / 64), 256, 0, stream>>>(
        CTX, wot, bo, out, M, D_, NQ_);
}